// Round 1
// baseline (917.356 us; speedup 1.0000x reference)
//
#include <hip/hip_runtime.h>

// Problem constants
// B=512, L=128, N=64, H=16, PW=30, FEAT=480
#define LSX 65    // xs row stride (pad 64+1)
#define FSTR 52   // feat/w chunk row stride (48+4, float4-aligned)

__device__ __forceinline__ float fsig(float x) { return 1.f / (1.f + __expf(-x)); }
__device__ __forceinline__ float ftanh_(float x) { return 1.f - 2.f / (__expf(2.f * x) + 1.f); }

// ---------------------------------------------------------------------------
// Kernel 1: per (input i, batch b): dual-axis attention + conv/bn/pool + GEMM
// against Wih0 -> pre0[b_global, l, g]  (LSTM layer-0 input projection)
// grid = 1024 blocks (i*512+b), block = 256
// ---------------------------------------------------------------------------
__global__ __launch_bounds__(256) void k_attn_conv(
    const float* __restrict__ x1, const float* __restrict__ x2,
    const float* __restrict__ w_x_q, const float* __restrict__ w_x_k,
    const float* __restrict__ w_y_q, const float* __restrict__ w_y_k,
    const float* __restrict__ pos_emb,
    const float* __restrict__ conv_w, const float* __restrict__ conv_b,
    const float* __restrict__ bn_g, const float* __restrict__ bn_b,
    const float* __restrict__ bn_m, const float* __restrict__ bn_v,
    const float* __restrict__ Wih0,
    float* __restrict__ pre0)
{
    __shared__ float xs[128 * LSX];      // x, then attention-out in place
    __shared__ float feat_s[128 * FSTR]; // current K-chunk of feat (48 wide)
    __shared__ float w_s[64 * FSTR];     // current K-chunk of Wih0 (permuted)
    __shared__ float xk[64], ykv[128], uu[64], vv[128], sxs[128], sys[64];
    __shared__ float cw[16][4], cbs[16], bnsc[16], bnsh[16];

    const int bg = blockIdx.x;           // 0..1023
    const int t  = threadIdx.x;
    const float* x = (bg < 512 ? x1 : x2) + (size_t)(bg & 511) * 8192;

    // load x [128,64] coalesced
    #pragma unroll
    for (int r = 0; r < 32; ++r) {
        int pos = r * 256 + t;
        xs[(pos >> 6) * LSX + (pos & 63)] = x[pos];
    }
    if (t < 16) {
        float sc = bn_g[t] * rsqrtf(bn_v[t] + 1e-5f);
        bnsc[t] = sc;
        bnsh[t] = bn_b[t] - bn_m[t] * sc;
        cbs[t]  = conv_b[t];
        cw[t][0] = conv_w[t * 4 + 0]; cw[t][1] = conv_w[t * 4 + 1];
        cw[t][2] = conv_w[t * 4 + 2]; cw[t][3] = conv_w[t * 4 + 3];
    }
    __syncthreads();

    // phase 1: x_k[n] = sum_l x[l,n]*w_x_k[l];  y_kv[l] = sum_n w_y_k[n]*x[l,n]
    if (t < 64) {
        float s = 0.f;
        for (int l = 0; l < 128; ++l) s += xs[l * LSX + t] * w_x_k[l];
        xk[t] = s;
    } else if (t < 192) {
        int l = t - 64;
        float s = 0.f;
        for (int n = 0; n < 64; ++n) s += w_y_k[n] * xs[l * LSX + n];
        ykv[l] = s;
    }
    __syncthreads();

    // phase 2: u[m] = sum_n w_x_q[m,n]*x_k[n];  v[m] = sum_l y_kv[l]*w_y_q[l,m]
    if (t < 64) {
        float s = 0.f;
        for (int n = 0; n < 64; ++n) s += w_x_q[t * 64 + n] * xk[n];
        uu[t] = s;
    } else if (t < 192) {
        int m = t - 64;
        float s = 0.f;
        for (int l = 0; l < 128; ++l) s += ykv[l] * w_y_q[l * 128 + m];
        vv[m] = s;
    }
    __syncthreads();

    // phase 3: s_x[l] = sum_m x[l,m]*u[m];  y_[n] = sum_m v[m]*x[m,n]
    if (t < 128) {
        float s = 0.f;
        for (int m = 0; m < 64; ++m) s += xs[t * LSX + m] * uu[m];
        sxs[t] = s;
    } else if (t < 192) {
        int n = t - 128;
        float s = 0.f;
        for (int m = 0; m < 128; ++m) s += vv[m] * xs[m * LSX + n];
        sys[n] = s;
    }
    __syncthreads();

    // phase 4: softmaxes (wave 0: sx over 128; wave 1: sy over 64), x10
    if (t < 64) {
        float a = sxs[t], b = sxs[t + 64];
        float mx = fmaxf(a, b);
        #pragma unroll
        for (int d = 32; d > 0; d >>= 1) mx = fmaxf(mx, __shfl_xor(mx, d, 64));
        float e0 = __expf(a - mx), e1 = __expf(b - mx);
        float s = e0 + e1;
        #pragma unroll
        for (int d = 32; d > 0; d >>= 1) s += __shfl_xor(s, d, 64);
        float r = 10.f / s;
        sxs[t] = e0 * r; sxs[t + 64] = e1 * r;
    } else if (t < 128) {
        int n = t - 64;
        float a = sys[n];
        float mx = a;
        #pragma unroll
        for (int d = 32; d > 0; d >>= 1) mx = fmaxf(mx, __shfl_xor(mx, d, 64));
        float e = __expf(a - mx);
        float s = e;
        #pragma unroll
        for (int d = 32; d > 0; d >>= 1) s += __shfl_xor(s, d, 64);
        sys[n] = e * (10.f / s);
    }
    __syncthreads();

    // phase 5: out[l,n] = x*sx[l]*sy[n] + pos_emb  (in place)
    #pragma unroll
    for (int r = 0; r < 32; ++r) {
        int pos = r * 256 + t;
        int l = pos >> 6, n = pos & 63;
        xs[l * LSX + n] = xs[l * LSX + n] * sxs[l] * sys[n] + pos_emb[pos];
    }
    __syncthreads();

    // phase 6: conv+bn+pool -> feat chunks (K permuted: f' = q*16+h),
    // GEMM pre0[l,g] = sum_f feat[l,f]*Wih0[g,f]
    float acc[4][8];
    #pragma unroll
    for (int jj = 0; jj < 4; ++jj)
        #pragma unroll
        for (int gi = 0; gi < 8; ++gi) acc[jj][gi] = 0.f;

    const int lr = t >> 3;          // 0..31 (+32j covers 128 rows)
    const int gc = (t & 7) * 8;     // 8 consecutive g columns

    for (int ch = 0; ch < 10; ++ch) {
        const int q0 = ch * 3;
        // stage Wih0 chunk: w_s[g][ (q-q0)*16 + h ] = Wih0[g, h*30+q]
        #pragma unroll
        for (int it = 0; it < 12; ++it) {
            int pos = it * 256 + t;        // < 3072 = 64*48
            int g = pos / 48, fl = pos % 48;
            int q = q0 + (fl >> 4), h = fl & 15;
            w_s[g * FSTR + fl] = Wih0[g * 480 + h * 30 + q];
        }
        // feat chunk: tasks (l, qi) 128*3=384
        #pragma unroll
        for (int it = 0; it < 2; ++it) {
            int task = it * 256 + t;
            if (task < 384) {
                int l = task & 127, qi = task >> 7;
                int q = q0 + qi;
                const float* xr = &xs[l * LSX + 2 * q];
                float o0 = xr[0], o1 = xr[1], o2 = xr[2], o3 = xr[3], o4 = xr[4];
                float* fr = &feat_s[l * FSTR + qi * 16];
                #pragma unroll
                for (int h = 0; h < 16; ++h) {
                    float a = o0 * cw[h][0] + o1 * cw[h][1] + o2 * cw[h][2] + o3 * cw[h][3] + cbs[h];
                    float b = o1 * cw[h][0] + o2 * cw[h][1] + o3 * cw[h][2] + o4 * cw[h][3] + cbs[h];
                    a = fmaxf(a, 0.f) * bnsc[h] + bnsh[h];   // relu then BN affine
                    b = fmaxf(b, 0.f) * bnsc[h] + bnsh[h];
                    fr[h] = fmaxf(a, b);                     // maxpool(1,2)
                }
            }
        }
        __syncthreads();
        // GEMM accumulate over this 48-wide K-chunk
        #pragma unroll
        for (int f = 0; f < 48; f += 4) {
            float4 wv[8];
            #pragma unroll
            for (int gi = 0; gi < 8; ++gi)
                wv[gi] = *(const float4*)&w_s[(gc + gi) * FSTR + f];
            #pragma unroll
            for (int jj = 0; jj < 4; ++jj) {
                float4 av = *(const float4*)&feat_s[(lr + 32 * jj) * FSTR + f];
                #pragma unroll
                for (int gi = 0; gi < 8; ++gi)
                    acc[jj][gi] += av.x * wv[gi].x + av.y * wv[gi].y +
                                   av.z * wv[gi].z + av.w * wv[gi].w;
            }
        }
        __syncthreads();
    }

    // store pre0 (no bias; LSTM kernel adds bih0+bhh0)
    #pragma unroll
    for (int jj = 0; jj < 4; ++jj) {
        int l = lr + 32 * jj;
        float* dst = pre0 + ((size_t)bg * 128 + l) * 64 + gc;
        #pragma unroll
        for (int gi = 0; gi < 8; ++gi) dst[gi] = acc[jj][gi];
    }
}

// ---------------------------------------------------------------------------
// Kernel 2: fused 2-layer LSTM recurrence. 256 independent sequences
// (2 inputs x 128 "rows"), one 64-lane wave each; lane k owns gate element k.
// grid = 256, block = 64
// ---------------------------------------------------------------------------
__global__ __launch_bounds__(64) void k_lstm(
    const float* __restrict__ pre0,
    const float* __restrict__ Whh0,
    const float* __restrict__ Wih1, const float* __restrict__ Whh1,
    const float* __restrict__ bih0, const float* __restrict__ bhh0,
    const float* __restrict__ bih1, const float* __restrict__ bhh1,
    float* __restrict__ fbuf)
{
    const int blk = blockIdx.x;
    const int i = blk >> 7, j = blk & 127;
    const int k = threadIdx.x;

    float w0[16], wi1[16], wh1[16];
    #pragma unroll
    for (int m = 0; m < 16; ++m) {
        w0[m]  = Whh0[k * 16 + m];
        wi1[m] = Wih1[k * 16 + m];
        wh1[m] = Whh1[k * 16 + m];
    }
    const float b0 = bih0[k] + bhh0[k];
    const float b1 = bih1[k] + bhh1[k];

    float h0[16], h1[16];
    #pragma unroll
    for (int m = 0; m < 16; ++m) { h0[m] = 0.f; h1[m] = 0.f; }
    float c0 = 0.f, c1 = 0.f;

    __shared__ __align__(16) float hb0[16];
    __shared__ __align__(16) float hb1[16];

    const float* pp = pre0 + (size_t)i * 4194304 + (size_t)j * 64 + k;
    float* fb = fbuf + (size_t)i * 1048576 + (size_t)j * 16 + k;

    float pre_c = pp[0];
    const int l16 = (k + 16) & 63, l32 = (k + 32) & 63, l48 = (k + 48) & 63;

    for (int t = 0; t < 512; ++t) {
        float pre_n = pp[(size_t)(t + 1) * 8192];   // padded tail, value unused at t=511

        // ---- layer 0: gate k = pre + b0 + h0 . Whh0[k,:]
        float sA = 0.f, sB = 0.f, sC = 0.f, sD = 0.f;
        #pragma unroll
        for (int m = 0; m < 4; ++m) {
            sA += h0[m]      * w0[m];
            sB += h0[m + 4]  * w0[m + 4];
            sC += h0[m + 8]  * w0[m + 8];
            sD += h0[m + 12] * w0[m + 12];
        }
        float g0 = pre_c + b0 + ((sA + sB) + (sC + sD));
        float gf = __shfl(g0, l16, 64);
        float gg = __shfl(g0, l32, 64);
        float go = __shfl(g0, l48, 64);
        float ii = fsig(g0), ff = fsig(gf), gz = ftanh_(gg), oo = fsig(go);
        c0 = ff * c0 + ii * gz;
        float h0n = oo * ftanh_(c0);            // valid for k<16
        if (k < 16) hb0[k] = h0n;
        __syncthreads();
        float hn[16];
        *(float4*)&hn[0]  = *(const float4*)&hb0[0];
        *(float4*)&hn[4]  = *(const float4*)&hb0[4];
        *(float4*)&hn[8]  = *(const float4*)&hb0[8];
        *(float4*)&hn[12] = *(const float4*)&hb0[12];

        // ---- layer 1: gate k = b1 + hn . Wih1[k,:] + h1 . Whh1[k,:]
        float tA = 0.f, tB = 0.f, tC = 0.f, tD = 0.f;
        #pragma unroll
        for (int m = 0; m < 4; ++m) {
            tA += hn[m]      * wi1[m]      + h1[m]      * wh1[m];
            tB += hn[m + 4]  * wi1[m + 4]  + h1[m + 4]  * wh1[m + 4];
            tC += hn[m + 8]  * wi1[m + 8]  + h1[m + 8]  * wh1[m + 8];
            tD += hn[m + 12] * wi1[m + 12] + h1[m + 12] * wh1[m + 12];
        }
        float g1 = b1 + ((tA + tB) + (tC + tD));
        float gf1 = __shfl(g1, l16, 64);
        float gg1 = __shfl(g1, l32, 64);
        float go1 = __shfl(g1, l48, 64);
        float ii1 = fsig(g1), ff1 = fsig(gf1), gz1 = ftanh_(gg1), oo1 = fsig(go1);
        c1 = ff1 * c1 + ii1 * gz1;
        float h1n = oo1 * ftanh_(c1);
        if (k < 16) { hb1[k] = h1n; fb[(size_t)t * 2048] = h1n; }
        __syncthreads();
        *(float4*)&h1[0]  = *(const float4*)&hb1[0];
        *(float4*)&h1[4]  = *(const float4*)&hb1[4];
        *(float4*)&h1[8]  = *(const float4*)&hb1[8];
        *(float4*)&h1[12] = *(const float4*)&hb1[12];
        #pragma unroll
        for (int m = 0; m < 16; ++m) h0[m] = hn[m];
        pre_c = pre_n;
    }
}

// ---------------------------------------------------------------------------
// Kernel 3/4: fp32 GEMM C = leaky(A @ W^T + bias). A[M,K], W[N,K] both K-major.
// 64x64 tile, 4x4 per thread, k-chunks of 32 staged transposed in LDS,
// register-prefetch double buffering.
// ---------------------------------------------------------------------------
__global__ __launch_bounds__(256) void k_fc(
    const float* __restrict__ A, const float* __restrict__ W,
    const float* __restrict__ bias, float* __restrict__ C,
    int M, int N, int K, int leaky)
{
    __shared__ float As[32][68];
    __shared__ float Bs[32][68];
    const int t  = threadIdx.x;
    const int tx = t & 15, ty = t >> 4;
    const int m0 = blockIdx.y * 64, n0 = blockIdx.x * 64;

    const int f4a = t * 2, f4b = t * 2 + 1;      // 512 float4 slots (64 rows x 8)
    const int rA0 = f4a >> 3, kA0 = (f4a & 7) * 4;
    const int rA1 = f4b >> 3, kA1 = (f4b & 7) * 4;

    float4 pa0 = *(const float4*)&A[(size_t)(m0 + rA0) * K + kA0];
    float4 pa1 = *(const float4*)&A[(size_t)(m0 + rA1) * K + kA1];
    float4 pb0 = *(const float4*)&W[(size_t)(n0 + rA0) * K + kA0];
    float4 pb1 = *(const float4*)&W[(size_t)(n0 + rA1) * K + kA1];

    float acc[4][4];
    #pragma unroll
    for (int a = 0; a < 4; ++a)
        #pragma unroll
        for (int b = 0; b < 4; ++b) acc[a][b] = 0.f;

    for (int kc = 0; kc < K; kc += 32) {
        As[kA0 + 0][rA0] = pa0.x; As[kA0 + 1][rA0] = pa0.y;
        As[kA0 + 2][rA0] = pa0.z; As[kA0 + 3][rA0] = pa0.w;
        As[kA1 + 0][rA1] = pa1.x; As[kA1 + 1][rA1] = pa1.y;
        As[kA1 + 2][rA1] = pa1.z; As[kA1 + 3][rA1] = pa1.w;
        Bs[kA0 + 0][rA0] = pb0.x; Bs[kA0 + 1][rA0] = pb0.y;
        Bs[kA0 + 2][rA0] = pb0.z; Bs[kA0 + 3][rA0] = pb0.w;
        Bs[kA1 + 0][rA1] = pb1.x; Bs[kA1 + 1][rA1] = pb1.y;
        Bs[kA1 + 2][rA1] = pb1.z; Bs[kA1 + 3][rA1] = pb1.w;
        __syncthreads();
        if (kc + 32 < K) {
            pa0 = *(const float4*)&A[(size_t)(m0 + rA0) * K + kc + 32 + kA0];
            pa1 = *(const float4*)&A[(size_t)(m0 + rA1) * K + kc + 32 + kA1];
            pb0 = *(const float4*)&W[(size_t)(n0 + rA0) * K + kc + 32 + kA0];
            pb1 = *(const float4*)&W[(size_t)(n0 + rA1) * K + kc + 32 + kA1];
        }
        #pragma unroll
        for (int kk = 0; kk < 32; ++kk) {
            float4 a = *(const float4*)&As[kk][ty * 4];
            float4 b = *(const float4*)&Bs[kk][tx * 4];
            acc[0][0] += a.x * b.x; acc[0][1] += a.x * b.y; acc[0][2] += a.x * b.z; acc[0][3] += a.x * b.w;
            acc[1][0] += a.y * b.x; acc[1][1] += a.y * b.y; acc[1][2] += a.y * b.z; acc[1][3] += a.y * b.w;
            acc[2][0] += a.z * b.x; acc[2][1] += a.z * b.y; acc[2][2] += a.z * b.z; acc[2][3] += a.z * b.w;
            acc[3][0] += a.w * b.x; acc[3][1] += a.w * b.y; acc[3][2] += a.w * b.z; acc[3][3] += a.w * b.w;
        }
        __syncthreads();
    }
    #pragma unroll
    for (int ri = 0; ri < 4; ++ri) {
        int m = m0 + ty * 4 + ri;
        #pragma unroll
        for (int ci = 0; ci < 4; ++ci) {
            int n = n0 + tx * 4 + ci;
            float v = acc[ri][ci] + bias[n];
            if (leaky) v = (v > 0.f) ? v : 0.01f * v;
            C[(size_t)m * N + n] = v;
        }
    }
}

// ---------------------------------------------------------------------------
// Kernel 5: small FC3 [1024,1024] @ [20,1024]^T + bias -> d_out [1024,20]
// grid = 1024 (one block per row m)
// ---------------------------------------------------------------------------
__global__ __launch_bounds__(256) void k_fc3(
    const float* __restrict__ A, const float* __restrict__ W,
    const float* __restrict__ bias, float* __restrict__ out)
{
    __shared__ float row[1024];
    __shared__ float red[20][8];
    const int m = blockIdx.x;
    const int t = threadIdx.x;
    #pragma unroll
    for (int r = 0; r < 4; ++r) row[r * 256 + t] = A[(size_t)m * 1024 + r * 256 + t];
    __syncthreads();
    if (t < 160) {
        int o = t >> 3, seg = t & 7;
        const float* w = W + (size_t)o * 1024 + seg * 128;
        const float* rr = &row[seg * 128];
        float s = 0.f;
        for (int kk = 0; kk < 128; ++kk) s += rr[kk] * w[kk];
        red[o][seg] = s;
    }
    __syncthreads();
    if (t < 20) {
        float s = bias[t];
        #pragma unroll
        for (int seg = 0; seg < 8; ++seg) s += red[t][seg];
        out[(size_t)m * 20 + t] = s;
    }
}

// ---------------------------------------------------------------------------
extern "C" void kernel_launch(void* const* d_in, const int* in_sizes, int n_in,
                              void* d_out, int out_size, void* d_ws, size_t ws_size,
                              hipStream_t stream) {
    const float* in1    = (const float*)d_in[0];
    const float* in2    = (const float*)d_in[1];
    const float* w_x_q  = (const float*)d_in[2];
    const float* w_x_k  = (const float*)d_in[3];
    const float* w_y_q  = (const float*)d_in[4];
    const float* w_y_k  = (const float*)d_in[5];
    const float* posemb = (const float*)d_in[6];
    const float* conv_w = (const float*)d_in[7];
    const float* conv_b = (const float*)d_in[8];
    const float* bn_g   = (const float*)d_in[9];
    const float* bn_b   = (const float*)d_in[10];
    const float* bn_m   = (const float*)d_in[11];
    const float* bn_v   = (const float*)d_in[12];
    const float* Wih0   = (const float*)d_in[13];
    const float* Whh0   = (const float*)d_in[14];
    const float* bih0   = (const float*)d_in[15];
    const float* bhh0   = (const float*)d_in[16];
    const float* Wih1   = (const float*)d_in[17];
    const float* Whh1   = (const float*)d_in[18];
    const float* bih1   = (const float*)d_in[19];
    const float* bhh1   = (const float*)d_in[20];
    const float* fc1w   = (const float*)d_in[21];
    const float* fc1b   = (const float*)d_in[22];
    const float* fc2w   = (const float*)d_in[23];
    const float* fc2b   = (const float*)d_in[24];
    const float* fc3w   = (const float*)d_in[25];
    const float* fc3b   = (const float*)d_in[26];
    float* out = (float*)d_out;

    float* ws   = (float*)d_ws;
    float* pre0 = ws;                         // 2*512*128*64 (+8192 pad) = 8,396,800
    float* fbuf = ws + 8396800;               // 2*512*2048 = 2,097,152
    float* f1   = ws + 10493952;              // 1024*1024
    float* f2   = ws + 11542528;              // 1024*1024  (total ~50.4 MB)

    k_attn_conv<<<1024, 256, 0, stream>>>(in1, in2, w_x_q, w_x_k, w_y_q, w_y_k,
                                          posemb, conv_w, conv_b, bn_g, bn_b,
                                          bn_m, bn_v, Wih0, pre0);
    k_lstm<<<256, 64, 0, stream>>>(pre0, Whh0, Wih1, Whh1,
                                   bih0, bhh0, bih1, bhh1, fbuf);
    dim3 gfc(16, 16);
    k_fc<<<gfc, 256, 0, stream>>>(fbuf, fc1w, fc1b, f1, 1024, 1024, 2048, 1);
    k_fc<<<gfc, 256, 0, stream>>>(f1,   fc2w, fc2b, f2, 1024, 1024, 1024, 1);
    k_fc3<<<1024, 256, 0, stream>>>(f2, fc3w, fc3b, out);
}

// Round 2
// 785.313 us; speedup vs baseline: 1.1681x; 1.1681x over previous
//
#include <hip/hip_runtime.h>

// Problem constants: B=512, L=128, N=64, H=16, PW=30, FEAT=480
#define LSX 65    // xs row stride (64+1)
#define FS  52    // feat_s row stride (48+4, float4-aligned)
#define WSR 68    // w_s row stride (64+4, float4-aligned)

__device__ __forceinline__ float fsig(float x) { return 1.f / (1.f + __expf(-x)); }
__device__ __forceinline__ float ftanh_(float x) { return 1.f - 2.f / (__expf(2.f * x) + 1.f); }

// ---------------------------------------------------------------------------
// Kernel 0: permute Wih0 [64,480] -> Wp [480,64], f' = q*16+h, i.e.
// Wp[(q*16+h)*64 + g] = Wih0[g*480 + h*30 + q]
// ---------------------------------------------------------------------------
__global__ __launch_bounds__(256) void k_permW(const float* __restrict__ Wih0,
                                               float* __restrict__ Wp)
{
    int idx = blockIdx.x * 256 + threadIdx.x;     // < 30720
    int fp = idx >> 6, g = idx & 63;
    int q = fp >> 4, h = fp & 15;
    Wp[idx] = Wih0[g * 480 + h * 30 + q];
}

// ---------------------------------------------------------------------------
// Kernel 1: per (input i, batch b): dual-axis attention + conv/bn/pool + GEMM
// against Wp -> pre0[b_global, l, g]
// grid = 1024, block = 256
// ---------------------------------------------------------------------------
__global__ __launch_bounds__(256) void k_attn_conv(
    const float* __restrict__ x1, const float* __restrict__ x2,
    const float* __restrict__ w_x_q, const float* __restrict__ w_x_k,
    const float* __restrict__ w_y_q, const float* __restrict__ w_y_k,
    const float* __restrict__ pos_emb,
    const float* __restrict__ conv_w, const float* __restrict__ conv_b,
    const float* __restrict__ bn_g, const float* __restrict__ bn_b,
    const float* __restrict__ bn_m, const float* __restrict__ bn_v,
    const float* __restrict__ Wp,
    float* __restrict__ pre0)
{
    __shared__ float xs[128 * LSX];      // x, then attention-out in place
    __shared__ float feat_s[128 * FS];   // current K-chunk of feat (48 wide)
    __shared__ float w_s[48 * WSR];      // current K-chunk of W, transposed [f][g]
    __shared__ float xk[64], ykv[128], uu[64], vv[128], sxs[128], sys[64];
    __shared__ float cw[16][4], cbs[16], bnsc[16], bnsh[16];

    const int bg = blockIdx.x;           // 0..1023
    const int t  = threadIdx.x;
    const float* x = (bg < 512 ? x1 : x2) + (size_t)(bg & 511) * 8192;

    // load x [128,64] coalesced
    #pragma unroll
    for (int r = 0; r < 32; ++r) {
        int pos = r * 256 + t;
        xs[(pos >> 6) * LSX + (pos & 63)] = x[pos];
    }
    if (t < 16) {
        float sc = bn_g[t] * rsqrtf(bn_v[t] + 1e-5f);
        bnsc[t] = sc;
        bnsh[t] = bn_b[t] - bn_m[t] * sc;
        cbs[t]  = conv_b[t];
        cw[t][0] = conv_w[t * 4 + 0]; cw[t][1] = conv_w[t * 4 + 1];
        cw[t][2] = conv_w[t * 4 + 2]; cw[t][3] = conv_w[t * 4 + 3];
    }
    __syncthreads();

    // phase 1: x_k[n] = sum_l x[l,n]*w_x_k[l];  y_kv[l] = sum_n w_y_k[n]*x[l,n]
    if (t < 64) {
        float s = 0.f;
        for (int l = 0; l < 128; ++l) s += xs[l * LSX + t] * w_x_k[l];
        xk[t] = s;
    } else if (t < 192) {
        int l = t - 64;
        float s = 0.f;
        for (int n = 0; n < 64; ++n) s += w_y_k[n] * xs[l * LSX + n];
        ykv[l] = s;
    }
    __syncthreads();

    // phase 2: u[m] = sum_n w_x_q[m,n]*x_k[n];  v[m] = sum_l y_kv[l]*w_y_q[l,m]
    if (t < 64) {
        float s = 0.f;
        for (int n = 0; n < 64; ++n) s += w_x_q[t * 64 + n] * xk[n];
        uu[t] = s;
    } else if (t < 192) {
        int m = t - 64;
        float s = 0.f;
        for (int l = 0; l < 128; ++l) s += ykv[l] * w_y_q[l * 128 + m];
        vv[m] = s;
    }
    __syncthreads();

    // phase 3: s_x[l] = sum_m x[l,m]*u[m];  y_[n] = sum_m v[m]*x[m,n]
    if (t < 128) {
        float s = 0.f;
        for (int m = 0; m < 64; ++m) s += xs[t * LSX + m] * uu[m];
        sxs[t] = s;
    } else if (t < 192) {
        int n = t - 128;
        float s = 0.f;
        for (int m = 0; m < 128; ++m) s += vv[m] * xs[m * LSX + n];
        sys[n] = s;
    }
    __syncthreads();

    // phase 4: softmaxes, x10
    if (t < 64) {
        float a = sxs[t], b = sxs[t + 64];
        float mx = fmaxf(a, b);
        #pragma unroll
        for (int d = 32; d > 0; d >>= 1) mx = fmaxf(mx, __shfl_xor(mx, d, 64));
        float e0 = __expf(a - mx), e1 = __expf(b - mx);
        float s = e0 + e1;
        #pragma unroll
        for (int d = 32; d > 0; d >>= 1) s += __shfl_xor(s, d, 64);
        float r = 10.f / s;
        sxs[t] = e0 * r; sxs[t + 64] = e1 * r;
    } else if (t < 128) {
        int n = t - 64;
        float a = sys[n];
        float mx = a;
        #pragma unroll
        for (int d = 32; d > 0; d >>= 1) mx = fmaxf(mx, __shfl_xor(mx, d, 64));
        float e = __expf(a - mx);
        float s = e;
        #pragma unroll
        for (int d = 32; d > 0; d >>= 1) s += __shfl_xor(s, d, 64);
        sys[n] = e * (10.f / s);
    }
    __syncthreads();

    // phase 5: out[l,n] = x*sx[l]*sy[n] + pos_emb  (in place)
    #pragma unroll
    for (int r = 0; r < 32; ++r) {
        int pos = r * 256 + t;
        int l = pos >> 6, n = pos & 63;
        xs[l * LSX + n] = xs[l * LSX + n] * sxs[l] * sys[n] + pos_emb[pos];
    }
    __syncthreads();

    // phase 6: per 48-wide K-chunk: stage W (transposed) + conv feat, then GEMM
    const int tx = t & 15;               // g-block: cols tx*4 .. tx*4+3
    const int ty = t >> 4;               // l-block: rows ty*4 .. ty*4+3 (+64*jj)
    float acc[2][4][4];
    #pragma unroll
    for (int jj = 0; jj < 2; ++jj)
        #pragma unroll
        for (int r = 0; r < 4; ++r)
            #pragma unroll
            for (int c = 0; c < 4; ++c) acc[jj][r][c] = 0.f;

    for (int ch = 0; ch < 10; ++ch) {
        // stage w_s[fl][g] <- Wp[ch*3072 + fl*64 + g], 768 float4 (3/thread)
        const float* wsrc = Wp + ch * 3072;
        #pragma unroll
        for (int it = 0; it < 3; ++it) {
            int idx = it * 256 + t;              // 0..767
            int fl = idx >> 4, gq = (idx & 15) * 4;
            *(float4*)&w_s[fl * WSR + gq] = *(const float4*)&wsrc[idx * 4];
        }
        // conv+bn+pool feat chunk: 384 tasks (l, qi)
        #pragma unroll
        for (int it = 0; it < 2; ++it) {
            int task = it * 256 + t;
            if (task < 384) {
                int l = task & 127, qi = task >> 7;
                int q = ch * 3 + qi;
                const float* xr = &xs[l * LSX + 2 * q];
                float o0 = xr[0], o1 = xr[1], o2 = xr[2], o3 = xr[3], o4 = xr[4];
                float4 fv[4];
                float* fp = (float*)fv;
                #pragma unroll
                for (int h = 0; h < 16; ++h) {
                    float a = o0 * cw[h][0] + o1 * cw[h][1] + o2 * cw[h][2] + o3 * cw[h][3] + cbs[h];
                    float b = o1 * cw[h][0] + o2 * cw[h][1] + o3 * cw[h][2] + o4 * cw[h][3] + cbs[h];
                    a = fmaxf(a, 0.f) * bnsc[h] + bnsh[h];
                    b = fmaxf(b, 0.f) * bnsc[h] + bnsh[h];
                    fp[h] = fmaxf(a, b);
                }
                float* fr = &feat_s[l * FS + qi * 16];
                *(float4*)&fr[0]  = fv[0];
                *(float4*)&fr[4]  = fv[1];
                *(float4*)&fr[8]  = fv[2];
                *(float4*)&fr[12] = fv[3];
            }
        }
        __syncthreads();

        // GEMM accumulate: acc[jj][r][c] += feat[l, f..f+3] . w[f..f+3, g]
        #pragma unroll
        for (int f = 0; f < 48; f += 4) {
            float4 b0 = *(const float4*)&w_s[(f + 0) * WSR + tx * 4];
            float4 b1 = *(const float4*)&w_s[(f + 1) * WSR + tx * 4];
            float4 b2 = *(const float4*)&w_s[(f + 2) * WSR + tx * 4];
            float4 b3 = *(const float4*)&w_s[(f + 3) * WSR + tx * 4];
            #pragma unroll
            for (int jj = 0; jj < 2; ++jj) {
                #pragma unroll
                for (int r = 0; r < 4; ++r) {
                    float4 av = *(const float4*)&feat_s[(jj * 64 + ty * 4 + r) * FS + f];
                    acc[jj][r][0] += av.x * b0.x + av.y * b1.x + av.z * b2.x + av.w * b3.x;
                    acc[jj][r][1] += av.x * b0.y + av.y * b1.y + av.z * b2.y + av.w * b3.y;
                    acc[jj][r][2] += av.x * b0.z + av.y * b1.z + av.z * b2.z + av.w * b3.z;
                    acc[jj][r][3] += av.x * b0.w + av.y * b1.w + av.z * b2.w + av.w * b3.w;
                }
            }
        }
        __syncthreads();
    }

    // store pre0 (no bias; LSTM kernel adds bih0+bhh0)
    #pragma unroll
    for (int jj = 0; jj < 2; ++jj) {
        #pragma unroll
        for (int r = 0; r < 4; ++r) {
            int l = jj * 64 + ty * 4 + r;
            float4 v = make_float4(acc[jj][r][0], acc[jj][r][1], acc[jj][r][2], acc[jj][r][3]);
            *(float4*)&pre0[((size_t)bg * 128 + l) * 64 + tx * 4] = v;
        }
    }
}

// ---------------------------------------------------------------------------
// Kernel 2: fused 2-layer LSTM recurrence. 256 independent sequences,
// one 64-lane wave each; lane k owns gate element k.
// ---------------------------------------------------------------------------
__global__ __launch_bounds__(64) void k_lstm(
    const float* __restrict__ pre0,
    const float* __restrict__ Whh0,
    const float* __restrict__ Wih1, const float* __restrict__ Whh1,
    const float* __restrict__ bih0, const float* __restrict__ bhh0,
    const float* __restrict__ bih1, const float* __restrict__ bhh1,
    float* __restrict__ fbuf)
{
    const int blk = blockIdx.x;
    const int i = blk >> 7, j = blk & 127;
    const int k = threadIdx.x;

    float w0[16], wi1[16], wh1[16];
    #pragma unroll
    for (int m = 0; m < 16; ++m) {
        w0[m]  = Whh0[k * 16 + m];
        wi1[m] = Wih1[k * 16 + m];
        wh1[m] = Whh1[k * 16 + m];
    }
    const float b0 = bih0[k] + bhh0[k];
    const float b1 = bih1[k] + bhh1[k];

    float h0[16], h1[16];
    #pragma unroll
    for (int m = 0; m < 16; ++m) { h0[m] = 0.f; h1[m] = 0.f; }
    float c0 = 0.f, c1 = 0.f;

    __shared__ __align__(16) float hb0[16];
    __shared__ __align__(16) float hb1[16];

    const float* pp = pre0 + (size_t)i * 4194304 + (size_t)j * 64 + k;
    float* fb = fbuf + (size_t)i * 1048576 + (size_t)j * 16 + k;

    float pre_c = pp[0];
    const int l16 = (k + 16) & 63, l32 = (k + 32) & 63, l48 = (k + 48) & 63;

    for (int t = 0; t < 512; ++t) {
        float pre_n = pp[(size_t)(t + 1) * 8192];   // padded tail, unused at t=511

        // ---- layer 0
        float sA = 0.f, sB = 0.f, sC = 0.f, sD = 0.f;
        #pragma unroll
        for (int m = 0; m < 4; ++m) {
            sA += h0[m]      * w0[m];
            sB += h0[m + 4]  * w0[m + 4];
            sC += h0[m + 8]  * w0[m + 8];
            sD += h0[m + 12] * w0[m + 12];
        }
        float g0 = pre_c + b0 + ((sA + sB) + (sC + sD));
        float gf = __shfl(g0, l16, 64);
        float gg = __shfl(g0, l32, 64);
        float go = __shfl(g0, l48, 64);
        float ii = fsig(g0), ff = fsig(gf), gz = ftanh_(gg), oo = fsig(go);
        c0 = ff * c0 + ii * gz;
        float h0n = oo * ftanh_(c0);            // valid for k<16
        if (k < 16) hb0[k] = h0n;
        __syncthreads();
        float hn[16];
        *(float4*)&hn[0]  = *(const float4*)&hb0[0];
        *(float4*)&hn[4]  = *(const float4*)&hb0[4];
        *(float4*)&hn[8]  = *(const float4*)&hb0[8];
        *(float4*)&hn[12] = *(const float4*)&hb0[12];

        // ---- layer 1
        float tA = 0.f, tB = 0.f, tC = 0.f, tD = 0.f;
        #pragma unroll
        for (int m = 0; m < 4; ++m) {
            tA += hn[m]      * wi1[m]      + h1[m]      * wh1[m];
            tB += hn[m + 4]  * wi1[m + 4]  + h1[m + 4]  * wh1[m + 4];
            tC += hn[m + 8]  * wi1[m + 8]  + h1[m + 8]  * wh1[m + 8];
            tD += hn[m + 12] * wi1[m + 12] + h1[m + 12] * wh1[m + 12];
        }
        float g1 = b1 + ((tA + tB) + (tC + tD));
        float gf1 = __shfl(g1, l16, 64);
        float gg1 = __shfl(g1, l32, 64);
        float go1 = __shfl(g1, l48, 64);
        float ii1 = fsig(g1), ff1 = fsig(gf1), gz1 = ftanh_(gg1), oo1 = fsig(go1);
        c1 = ff1 * c1 + ii1 * gz1;
        float h1n = oo1 * ftanh_(c1);
        if (k < 16) { hb1[k] = h1n; fb[(size_t)t * 2048] = h1n; }
        __syncthreads();
        *(float4*)&h1[0]  = *(const float4*)&hb1[0];
        *(float4*)&h1[4]  = *(const float4*)&hb1[4];
        *(float4*)&h1[8]  = *(const float4*)&hb1[8];
        *(float4*)&h1[12] = *(const float4*)&hb1[12];
        #pragma unroll
        for (int m = 0; m < 16; ++m) h0[m] = hn[m];
        pre_c = pre_n;
    }
}

// ---------------------------------------------------------------------------
// Kernel 3/4: fp32 GEMM C = leaky(A @ W^T + bias). 64x64 tile, 4x4/thread.
// ---------------------------------------------------------------------------
__global__ __launch_bounds__(256) void k_fc(
    const float* __restrict__ A, const float* __restrict__ W,
    const float* __restrict__ bias, float* __restrict__ C,
    int M, int N, int K, int leaky)
{
    __shared__ float As[32][68];
    __shared__ float Bs[32][68];
    const int t  = threadIdx.x;
    const int tx = t & 15, ty = t >> 4;
    const int m0 = blockIdx.y * 64, n0 = blockIdx.x * 64;

    const int f4a = t * 2, f4b = t * 2 + 1;
    const int rA0 = f4a >> 3, kA0 = (f4a & 7) * 4;
    const int rA1 = f4b >> 3, kA1 = (f4b & 7) * 4;

    float4 pa0 = *(const float4*)&A[(size_t)(m0 + rA0) * K + kA0];
    float4 pa1 = *(const float4*)&A[(size_t)(m0 + rA1) * K + kA1];
    float4 pb0 = *(const float4*)&W[(size_t)(n0 + rA0) * K + kA0];
    float4 pb1 = *(const float4*)&W[(size_t)(n0 + rA1) * K + kA1];

    float acc[4][4];
    #pragma unroll
    for (int a = 0; a < 4; ++a)
        #pragma unroll
        for (int b = 0; b < 4; ++b) acc[a][b] = 0.f;

    for (int kc = 0; kc < K; kc += 32) {
        As[kA0 + 0][rA0] = pa0.x; As[kA0 + 1][rA0] = pa0.y;
        As[kA0 + 2][rA0] = pa0.z; As[kA0 + 3][rA0] = pa0.w;
        As[kA1 + 0][rA1] = pa1.x; As[kA1 + 1][rA1] = pa1.y;
        As[kA1 + 2][rA1] = pa1.z; As[kA1 + 3][rA1] = pa1.w;
        Bs[kA0 + 0][rA0] = pb0.x; Bs[kA0 + 1][rA0] = pb0.y;
        Bs[kA0 + 2][rA0] = pb0.z; Bs[kA0 + 3][rA0] = pb0.w;
        Bs[kA1 + 0][rA1] = pb1.x; Bs[kA1 + 1][rA1] = pb1.y;
        Bs[kA1 + 2][rA1] = pb1.z; Bs[kA1 + 3][rA1] = pb1.w;
        __syncthreads();
        if (kc + 32 < K) {
            pa0 = *(const float4*)&A[(size_t)(m0 + rA0) * K + kc + 32 + kA0];
            pa1 = *(const float4*)&A[(size_t)(m0 + rA1) * K + kc + 32 + kA1];
            pb0 = *(const float4*)&W[(size_t)(n0 + rA0) * K + kc + 32 + kA0];
            pb1 = *(const float4*)&W[(size_t)(n0 + rA1) * K + kc + 32 + kA1];
        }
        #pragma unroll
        for (int kk = 0; kk < 32; ++kk) {
            float4 a = *(const float4*)&As[kk][ty * 4];
            float4 b = *(const float4*)&Bs[kk][tx * 4];
            acc[0][0] += a.x * b.x; acc[0][1] += a.x * b.y; acc[0][2] += a.x * b.z; acc[0][3] += a.x * b.w;
            acc[1][0] += a.y * b.x; acc[1][1] += a.y * b.y; acc[1][2] += a.y * b.z; acc[1][3] += a.y * b.w;
            acc[2][0] += a.z * b.x; acc[2][1] += a.z * b.y; acc[2][2] += a.z * b.z; acc[2][3] += a.z * b.w;
            acc[3][0] += a.w * b.x; acc[3][1] += a.w * b.y; acc[3][2] += a.w * b.z; acc[3][3] += a.w * b.w;
        }
        __syncthreads();
    }
    #pragma unroll
    for (int ri = 0; ri < 4; ++ri) {
        int m = m0 + ty * 4 + ri;
        #pragma unroll
        for (int ci = 0; ci < 4; ++ci) {
            int n = n0 + tx * 4 + ci;
            float v = acc[ri][ci] + bias[n];
            if (leaky) v = (v > 0.f) ? v : 0.01f * v;
            C[(size_t)m * N + n] = v;
        }
    }
}

// ---------------------------------------------------------------------------
// Kernel 5: FC3 [1024,1024] @ [20,1024]^T + bias -> d_out [1024,20]
// ---------------------------------------------------------------------------
__global__ __launch_bounds__(256) void k_fc3(
    const float* __restrict__ A, const float* __restrict__ W,
    const float* __restrict__ bias, float* __restrict__ out)
{
    __shared__ float row[1024];
    __shared__ float red[20][8];
    const int m = blockIdx.x;
    const int t = threadIdx.x;
    #pragma unroll
    for (int r = 0; r < 4; ++r) row[r * 256 + t] = A[(size_t)m * 1024 + r * 256 + t];
    __syncthreads();
    if (t < 160) {
        int o = t >> 3, seg = t & 7;
        const float* w = W + (size_t)o * 1024 + seg * 128;
        const float* rr = &row[seg * 128];
        float s = 0.f;
        for (int kk = 0; kk < 128; ++kk) s += rr[kk] * w[kk];
        red[o][seg] = s;
    }
    __syncthreads();
    if (t < 20) {
        float s = bias[t];
        #pragma unroll
        for (int seg = 0; seg < 8; ++seg) s += red[t][seg];
        out[(size_t)m * 20 + t] = s;
    }
}

// ---------------------------------------------------------------------------
extern "C" void kernel_launch(void* const* d_in, const int* in_sizes, int n_in,
                              void* d_out, int out_size, void* d_ws, size_t ws_size,
                              hipStream_t stream) {
    const float* in1    = (const float*)d_in[0];
    const float* in2    = (const float*)d_in[1];
    const float* w_x_q  = (const float*)d_in[2];
    const float* w_x_k  = (const float*)d_in[3];
    const float* w_y_q  = (const float*)d_in[4];
    const float* w_y_k  = (const float*)d_in[5];
    const float* posemb = (const float*)d_in[6];
    const float* conv_w = (const float*)d_in[7];
    const float* conv_b = (const float*)d_in[8];
    const float* bn_g   = (const float*)d_in[9];
    const float* bn_b   = (const float*)d_in[10];
    const float* bn_m   = (const float*)d_in[11];
    const float* bn_v   = (const float*)d_in[12];
    const float* Wih0   = (const float*)d_in[13];
    const float* Whh0   = (const float*)d_in[14];
    const float* bih0   = (const float*)d_in[15];
    const float* bhh0   = (const float*)d_in[16];
    const float* Wih1   = (const float*)d_in[17];
    const float* Whh1   = (const float*)d_in[18];
    const float* bih1   = (const float*)d_in[19];
    const float* bhh1   = (const float*)d_in[20];
    const float* fc1w   = (const float*)d_in[21];
    const float* fc1b   = (const float*)d_in[22];
    const float* fc2w   = (const float*)d_in[23];
    const float* fc2b   = (const float*)d_in[24];
    const float* fc3w   = (const float*)d_in[25];
    const float* fc3b   = (const float*)d_in[26];
    float* out = (float*)d_out;

    float* ws   = (float*)d_ws;
    float* pre0 = ws;                         // 8,396,800 floats (incl. lstm pad)
    float* fbuf = ws + 8396800;               // 2,097,152
    float* f1   = ws + 10493952;              // 1,048,576
    float* f2   = ws + 11542528;              // 1,048,576
    float* Wp   = ws + 12591104;              // 30,720  (total ~50.5 MB)

    k_permW<<<120, 256, 0, stream>>>(Wih0, Wp);
    k_attn_conv<<<1024, 256, 0, stream>>>(in1, in2, w_x_q, w_x_k, w_y_q, w_y_k,
                                          posemb, conv_w, conv_b, bn_g, bn_b,
                                          bn_m, bn_v, Wp, pre0);
    k_lstm<<<256, 64, 0, stream>>>(pre0, Whh0, Wih1, Whh1,
                                   bih0, bhh0, bih1, bhh1, fbuf);
    dim3 gfc(16, 16);
    k_fc<<<gfc, 256, 0, stream>>>(fbuf, fc1w, fc1b, f1, 1024, 1024, 2048, 1);
    k_fc<<<gfc, 256, 0, stream>>>(f1,   fc2w, fc2b, f2, 1024, 1024, 1024, 1);
    k_fc3<<<1024, 256, 0, stream>>>(f2, fc3w, fc3b, out);
}

// Round 3
// 456.598 us; speedup vs baseline: 2.0091x; 1.7199x over previous
//
#include <hip/hip_runtime.h>

// Problem constants: B=512, L=128, N=64, H=16, PW=30, FEAT=480
#define LSX 65    // xs row stride (64+1)
#define BST 40    // bf16 LDS row stride (32+8, 16B-aligned, 2-way banks)

typedef __bf16 bf16x8 __attribute__((ext_vector_type(8)));
typedef float  f32x4  __attribute__((ext_vector_type(4)));

__device__ __forceinline__ float fsig(float x)   { return __builtin_amdgcn_rcpf(1.f + __expf(-x)); }
__device__ __forceinline__ float ftanh_(float x) { return 1.f - 2.f * __builtin_amdgcn_rcpf(__expf(2.f * x) + 1.f); }

__device__ __forceinline__ unsigned short f2bf_rne(float x) {
    unsigned int u = __float_as_uint(x);
    unsigned int r = u + 0x7FFFu + ((u >> 16) & 1u);
    return (unsigned short)(r >> 16);
}

// ---------------------------------------------------------------------------
// Kernel 0: permute+split Wih0 [64,480] -> Wh/Wl [g][f'] bf16, f' = q*16+h
// ---------------------------------------------------------------------------
__global__ __launch_bounds__(256) void k_permW(const float* __restrict__ Wih0,
                                               unsigned short* __restrict__ Wh,
                                               unsigned short* __restrict__ Wl)
{
    int idx = blockIdx.x * 256 + threadIdx.x;     // < 30720 = 64*480
    int g = idx / 480, fp = idx % 480;
    int q = fp >> 4, h = fp & 15;
    float v = Wih0[g * 480 + h * 30 + q];
    unsigned int uv = __float_as_uint(v);
    unsigned short hb = (unsigned short)(uv >> 16);          // truncate
    float hf = __uint_as_float(uv & 0xFFFF0000u);
    Wh[idx] = hb;
    Wl[idx] = f2bf_rne(v - hf);
}

// ---------------------------------------------------------------------------
// Kernel 1: dual-axis attention + conv/bn/pool + MFMA GEMM (hi/lo bf16 split)
// grid = 1024 (i*512+b), block = 256 (4 waves)
// ---------------------------------------------------------------------------
__global__ __launch_bounds__(256) void k_attn_conv(
    const float* __restrict__ x1, const float* __restrict__ x2,
    const float* __restrict__ w_x_q, const float* __restrict__ w_x_k,
    const float* __restrict__ w_y_q, const float* __restrict__ w_y_k,
    const float* __restrict__ pos_emb,
    const float* __restrict__ conv_w, const float* __restrict__ conv_b,
    const float* __restrict__ bn_g, const float* __restrict__ bn_b,
    const float* __restrict__ bn_m, const float* __restrict__ bn_v,
    const unsigned short* __restrict__ Whg, const unsigned short* __restrict__ Wlg,
    float* __restrict__ pre0)
{
    __shared__ float xs[128 * LSX];              // x, then attention-out in place
    __shared__ unsigned short fh_s[128 * BST];   // feat chunk hi (bf16)
    __shared__ unsigned short fl_s[128 * BST];   // feat chunk lo
    __shared__ unsigned short wh_s[64 * BST];    // W chunk hi
    __shared__ unsigned short wl_s[64 * BST];    // W chunk lo
    __shared__ float xk[64], ykv[128], uu[64], vv[128], sxs[128], sys[64];
    __shared__ float cw[16][4], cbs[16], bnsc[16], bnsh[16];

    const int bg = blockIdx.x;
    const int t  = threadIdx.x;
    const float* x = (bg < 512 ? x1 : x2) + (size_t)(bg & 511) * 8192;

    #pragma unroll
    for (int r = 0; r < 32; ++r) {
        int pos = r * 256 + t;
        xs[(pos >> 6) * LSX + (pos & 63)] = x[pos];
    }
    if (t < 16) {
        float sc = bn_g[t] * rsqrtf(bn_v[t] + 1e-5f);
        bnsc[t] = sc;
        bnsh[t] = bn_b[t] - bn_m[t] * sc;
        cbs[t]  = conv_b[t];
        cw[t][0] = conv_w[t * 4 + 0]; cw[t][1] = conv_w[t * 4 + 1];
        cw[t][2] = conv_w[t * 4 + 2]; cw[t][3] = conv_w[t * 4 + 3];
    }
    __syncthreads();

    // phase 1
    if (t < 64) {
        float s = 0.f;
        for (int l = 0; l < 128; ++l) s += xs[l * LSX + t] * w_x_k[l];
        xk[t] = s;
    } else if (t < 192) {
        int l = t - 64;
        float s = 0.f;
        for (int n = 0; n < 64; ++n) s += w_y_k[n] * xs[l * LSX + n];
        ykv[l] = s;
    }
    __syncthreads();

    // phase 2
    if (t < 64) {
        float s = 0.f;
        for (int n = 0; n < 64; ++n) s += w_x_q[t * 64 + n] * xk[n];
        uu[t] = s;
    } else if (t < 192) {
        int m = t - 64;
        float s = 0.f;
        for (int l = 0; l < 128; ++l) s += ykv[l] * w_y_q[l * 128 + m];
        vv[m] = s;
    }
    __syncthreads();

    // phase 3
    if (t < 128) {
        float s = 0.f;
        for (int m = 0; m < 64; ++m) s += xs[t * LSX + m] * uu[m];
        sxs[t] = s;
    } else if (t < 192) {
        int n = t - 128;
        float s = 0.f;
        for (int m = 0; m < 128; ++m) s += vv[m] * xs[m * LSX + n];
        sys[n] = s;
    }
    __syncthreads();

    // phase 4: softmaxes, x10
    if (t < 64) {
        float a = sxs[t], b = sxs[t + 64];
        float mx = fmaxf(a, b);
        #pragma unroll
        for (int d = 32; d > 0; d >>= 1) mx = fmaxf(mx, __shfl_xor(mx, d, 64));
        float e0 = __expf(a - mx), e1 = __expf(b - mx);
        float s = e0 + e1;
        #pragma unroll
        for (int d = 32; d > 0; d >>= 1) s += __shfl_xor(s, d, 64);
        float r = 10.f / s;
        sxs[t] = e0 * r; sxs[t + 64] = e1 * r;
    } else if (t < 128) {
        int n = t - 64;
        float a = sys[n];
        float mx = a;
        #pragma unroll
        for (int d = 32; d > 0; d >>= 1) mx = fmaxf(mx, __shfl_xor(mx, d, 64));
        float e = __expf(a - mx);
        float s = e;
        #pragma unroll
        for (int d = 32; d > 0; d >>= 1) s += __shfl_xor(s, d, 64);
        sys[n] = e * (10.f / s);
    }
    __syncthreads();

    // phase 5: out = x*sx*sy + pos_emb (in place)
    #pragma unroll
    for (int r = 0; r < 32; ++r) {
        int pos = r * 256 + t;
        int l = pos >> 6, n = pos & 63;
        xs[l * LSX + n] = xs[l * LSX + n] * sxs[l] * sys[n] + pos_emb[pos];
    }
    __syncthreads();

    // phase 6: 15 K-chunks of 32 (2 conv-q each); MFMA with hi/lo split
    const int lane = t & 63, w = t >> 6;
    const int m16 = lane & 15, kb = (lane >> 4) * 8;
    const int cl = t & 127, cqi = t >> 7;        // conv task: l, qi

    f32x4 acc[2][4];
    #pragma unroll
    for (int mt = 0; mt < 2; ++mt)
        #pragma unroll
        for (int nt = 0; nt < 4; ++nt) {
            f32x4 z = {0.f, 0.f, 0.f, 0.f};
            acc[mt][nt] = z;
        }

    for (int ch = 0; ch < 15; ++ch) {
        // stage W chunk: [64 g][32 f] hi+lo, uint4 per thread per array
        {
            int g = t >> 2, fb = (t & 3) * 8;
            size_t src = (size_t)g * 480 + ch * 32 + fb;
            *(uint4*)&wh_s[g * BST + fb] = *(const uint4*)(Whg + src);
            *(uint4*)&wl_s[g * BST + fb] = *(const uint4*)(Wlg + src);
        }
        // conv+bn+pool: one task per thread -> 16 f' outputs, split hi/lo
        {
            int q = ch * 2 + cqi;
            const float* xr = &xs[cl * LSX + 2 * q];
            float o0 = xr[0], o1 = xr[1], o2 = xr[2], o3 = xr[3], o4 = xr[4];
            union U8 { unsigned short s[8]; uint4 v; };
            U8 h0u, h1u, l0u, l1u;
            #pragma unroll
            for (int h = 0; h < 16; ++h) {
                float a = o0 * cw[h][0] + o1 * cw[h][1] + o2 * cw[h][2] + o3 * cw[h][3] + cbs[h];
                float b = o1 * cw[h][0] + o2 * cw[h][1] + o3 * cw[h][2] + o4 * cw[h][3] + cbs[h];
                a = fmaxf(a, 0.f) * bnsc[h] + bnsh[h];
                b = fmaxf(b, 0.f) * bnsc[h] + bnsh[h];
                float v = fmaxf(a, b);
                unsigned int uv = __float_as_uint(v);
                unsigned short hb = (unsigned short)(uv >> 16);
                float hf = __uint_as_float(uv & 0xFFFF0000u);
                unsigned short lb = f2bf_rne(v - hf);
                if (h < 8) { h0u.s[h] = hb; l0u.s[h] = lb; }
                else       { h1u.s[h - 8] = hb; l1u.s[h - 8] = lb; }
            }
            int base = cl * BST + cqi * 16;
            *(uint4*)&fh_s[base]     = h0u.v;
            *(uint4*)&fh_s[base + 8] = h1u.v;
            *(uint4*)&fl_s[base]     = l0u.v;
            *(uint4*)&fl_s[base + 8] = l1u.v;
        }
        __syncthreads();

        // MFMA: wave w owns rows w*32..w*32+31, all 64 cols
        bf16x8 bh[4], bl[4], ah[2], al[2];
        #pragma unroll
        for (int nt = 0; nt < 4; ++nt) {
            int off = (nt * 16 + m16) * BST + kb;
            bh[nt] = *(const bf16x8*)&wh_s[off];
            bl[nt] = *(const bf16x8*)&wl_s[off];
        }
        #pragma unroll
        for (int mt = 0; mt < 2; ++mt) {
            int off = (w * 32 + mt * 16 + m16) * BST + kb;
            ah[mt] = *(const bf16x8*)&fh_s[off];
            al[mt] = *(const bf16x8*)&fl_s[off];
        }
        #pragma unroll
        for (int mt = 0; mt < 2; ++mt)
            #pragma unroll
            for (int nt = 0; nt < 4; ++nt) {
                acc[mt][nt] = __builtin_amdgcn_mfma_f32_16x16x32_bf16(ah[mt], bh[nt], acc[mt][nt], 0, 0, 0);
                acc[mt][nt] = __builtin_amdgcn_mfma_f32_16x16x32_bf16(al[mt], bh[nt], acc[mt][nt], 0, 0, 0);
                acc[mt][nt] = __builtin_amdgcn_mfma_f32_16x16x32_bf16(ah[mt], bl[nt], acc[mt][nt], 0, 0, 0);
            }
        __syncthreads();
    }

    // C/D layout: col = lane&15, row = (lane>>4)*4 + reg
    #pragma unroll
    for (int mt = 0; mt < 2; ++mt)
        #pragma unroll
        for (int nt = 0; nt < 4; ++nt)
            #pragma unroll
            for (int r = 0; r < 4; ++r) {
                int row = w * 32 + mt * 16 + (lane >> 4) * 4 + r;
                int col = nt * 16 + m16;
                pre0[(size_t)bg * 8192 + row * 64 + col] = acc[mt][nt][r];
            }
}

// ---------------------------------------------------------------------------
// Kernel 2: fused 2-layer LSTM. 256 sequences, one wave each, no LDS/barriers.
// h broadcast via readlane (-> SGPRs); 4-deep register prefetch of pre0.
// ---------------------------------------------------------------------------
__device__ __forceinline__ float lstm_cell(float gi, float gf, float gg, float go, float& c) {
    float ii = fsig(gi), ff = fsig(gf), gz = ftanh_(gg), oo = fsig(go);
    c = ff * c + ii * gz;
    return oo * ftanh_(c);
}

__global__ __launch_bounds__(64) void k_lstm(
    const float* __restrict__ pre0,
    const float* __restrict__ Whh0,
    const float* __restrict__ Wih1, const float* __restrict__ Whh1,
    const float* __restrict__ bih0, const float* __restrict__ bhh0,
    const float* __restrict__ bih1, const float* __restrict__ bhh1,
    float* __restrict__ fbuf)
{
    const int blk = blockIdx.x;
    const int i = blk >> 7, j = blk & 127;
    const int k = threadIdx.x;

    float w0[16], wi1[16], wh1[16];
    #pragma unroll
    for (int m = 0; m < 16; ++m) {
        w0[m]  = Whh0[k * 16 + m];
        wi1[m] = Wih1[k * 16 + m];
        wh1[m] = Whh1[k * 16 + m];
    }
    const float b0 = bih0[k] + bhh0[k];
    const float b1 = bih1[k] + bhh1[k];

    float h0[16], h1[16];
    #pragma unroll
    for (int m = 0; m < 16; ++m) { h0[m] = 0.f; h1[m] = 0.f; }
    float c0 = 0.f, c1 = 0.f;

    const float* pp = pre0 + (size_t)i * 4194304 + (size_t)j * 64 + k;
    float* fb = fbuf + (size_t)i * 1048576 + (size_t)j * 16 + k;

    const int l16 = (k + 16) & 63, l32 = (k + 32) & 63, l48 = (k + 48) & 63;

    float pf0 = pp[0], pf1 = pp[8192], pf2 = pp[2 * 8192], pf3 = pp[3 * 8192];

#define LSTM_STEP(PRE, TT)                                                          \
    {                                                                               \
        float sA = 0.f, sB = 0.f, sC = 0.f, sD = 0.f;                               \
        _Pragma("unroll")                                                           \
        for (int m = 0; m < 4; ++m) {                                               \
            sA += h0[m]      * w0[m];                                               \
            sB += h0[m + 4]  * w0[m + 4];                                           \
            sC += h0[m + 8]  * w0[m + 8];                                           \
            sD += h0[m + 12] * w0[m + 12];                                          \
        }                                                                           \
        float g0 = PRE + b0 + ((sA + sB) + (sC + sD));                              \
        float gf = __shfl(g0, l16, 64);                                             \
        float gg = __shfl(g0, l32, 64);                                             \
        float go = __shfl(g0, l48, 64);                                             \
        float h0n = lstm_cell(g0, gf, gg, go, c0);                                  \
        float hn[16];                                                               \
        _Pragma("unroll")                                                           \
        for (int m = 0; m < 16; ++m)                                                \
            hn[m] = __uint_as_float((unsigned int)__builtin_amdgcn_readlane(        \
                        (int)__float_as_uint(h0n), m));                             \
        float tA = 0.f, tB = 0.f, tC = 0.f, tD = 0.f;                               \
        _Pragma("unroll")                                                           \
        for (int m = 0; m < 4; ++m) {                                               \
            tA += hn[m]      * wi1[m]      + h1[m]      * wh1[m];                   \
            tB += hn[m + 4]  * wi1[m + 4]  + h1[m + 4]  * wh1[m + 4];               \
            tC += hn[m + 8]  * wi1[m + 8]  + h1[m + 8]  * wh1[m + 8];               \
            tD += hn[m + 12] * wi1[m + 12] + h1[m + 12] * wh1[m + 12];              \
        }                                                                           \
        float g1 = b1 + ((tA + tB) + (tC + tD));                                    \
        float gf1 = __shfl(g1, l16, 64);                                            \
        float gg1 = __shfl(g1, l32, 64);                                            \
        float go1 = __shfl(g1, l48, 64);                                            \
        float h1n = lstm_cell(g1, gf1, gg1, go1, c1);                               \
        if (k < 16) fb[(size_t)(TT) * 2048] = h1n;                                  \
        _Pragma("unroll")                                                           \
        for (int m = 0; m < 16; ++m) {                                              \
            h1[m] = __uint_as_float((unsigned int)__builtin_amdgcn_readlane(        \
                        (int)__float_as_uint(h1n), m));                             \
            h0[m] = hn[m];                                                          \
        }                                                                           \
    }

    for (int t = 0; t < 512; t += 4) {
        float n0 = pp[(size_t)(t + 4) * 8192];
        float n1 = pp[(size_t)(t + 5) * 8192];
        float n2 = pp[(size_t)(t + 6) * 8192];
        float n3 = pp[(size_t)(t + 7) * 8192];
        LSTM_STEP(pf0, t);
        LSTM_STEP(pf1, t + 1);
        LSTM_STEP(pf2, t + 2);
        LSTM_STEP(pf3, t + 3);
        pf0 = n0; pf1 = n1; pf2 = n2; pf3 = n3;
    }
#undef LSTM_STEP
}

// ---------------------------------------------------------------------------
// Kernel 3/4: fp32 GEMM C = leaky(A @ W^T + bias). 64x64 tile, 4x4/thread.
// ---------------------------------------------------------------------------
__global__ __launch_bounds__(256) void k_fc(
    const float* __restrict__ A, const float* __restrict__ W,
    const float* __restrict__ bias, float* __restrict__ C,
    int M, int N, int K, int leaky)
{
    __shared__ float As[32][68];
    __shared__ float Bs[32][68];
    const int t  = threadIdx.x;
    const int tx = t & 15, ty = t >> 4;
    const int m0 = blockIdx.y * 64, n0 = blockIdx.x * 64;

    const int f4a = t * 2, f4b = t * 2 + 1;
    const int rA0 = f4a >> 3, kA0 = (f4a & 7) * 4;
    const int rA1 = f4b >> 3, kA1 = (f4b & 7) * 4;

    float4 pa0 = *(const float4*)&A[(size_t)(m0 + rA0) * K + kA0];
    float4 pa1 = *(const float4*)&A[(size_t)(m0 + rA1) * K + kA1];
    float4 pb0 = *(const float4*)&W[(size_t)(n0 + rA0) * K + kA0];
    float4 pb1 = *(const float4*)&W[(size_t)(n0 + rA1) * K + kA1];

    float acc[4][4];
    #pragma unroll
    for (int a = 0; a < 4; ++a)
        #pragma unroll
        for (int b = 0; b < 4; ++b) acc[a][b] = 0.f;

    for (int kc = 0; kc < K; kc += 32) {
        As[kA0 + 0][rA0] = pa0.x; As[kA0 + 1][rA0] = pa0.y;
        As[kA0 + 2][rA0] = pa0.z; As[kA0 + 3][rA0] = pa0.w;
        As[kA1 + 0][rA1] = pa1.x; As[kA1 + 1][rA1] = pa1.y;
        As[kA1 + 2][rA1] = pa1.z; As[kA1 + 3][rA1] = pa1.w;
        Bs[kA0 + 0][rA0] = pb0.x; Bs[kA0 + 1][rA0] = pb0.y;
        Bs[kA0 + 2][rA0] = pb0.z; Bs[kA0 + 3][rA0] = pb0.w;
        Bs[kA1 + 0][rA1] = pb1.x; Bs[kA1 + 1][rA1] = pb1.y;
        Bs[kA1 + 2][rA1] = pb1.z; Bs[kA1 + 3][rA1] = pb1.w;
        __syncthreads();
        if (kc + 32 < K) {
            pa0 = *(const float4*)&A[(size_t)(m0 + rA0) * K + kc + 32 + kA0];
            pa1 = *(const float4*)&A[(size_t)(m0 + rA1) * K + kc + 32 + kA1];
            pb0 = *(const float4*)&W[(size_t)(n0 + rA0) * K + kc + 32 + kA0];
            pb1 = *(const float4*)&W[(size_t)(n0 + rA1) * K + kc + 32 + kA1];
        }
        #pragma unroll
        for (int kk = 0; kk < 32; ++kk) {
            float4 a = *(const float4*)&As[kk][ty * 4];
            float4 b = *(const float4*)&Bs[kk][tx * 4];
            acc[0][0] += a.x * b.x; acc[0][1] += a.x * b.y; acc[0][2] += a.x * b.z; acc[0][3] += a.x * b.w;
            acc[1][0] += a.y * b.x; acc[1][1] += a.y * b.y; acc[1][2] += a.y * b.z; acc[1][3] += a.y * b.w;
            acc[2][0] += a.z * b.x; acc[2][1] += a.z * b.y; acc[2][2] += a.z * b.z; acc[2][3] += a.z * b.w;
            acc[3][0] += a.w * b.x; acc[3][1] += a.w * b.y; acc[3][2] += a.w * b.z; acc[3][3] += a.w * b.w;
        }
        __syncthreads();
    }
    #pragma unroll
    for (int ri = 0; ri < 4; ++ri) {
        int m = m0 + ty * 4 + ri;
        #pragma unroll
        for (int ci = 0; ci < 4; ++ci) {
            int n = n0 + tx * 4 + ci;
            float v = acc[ri][ci] + bias[n];
            if (leaky) v = (v > 0.f) ? v : 0.01f * v;
            C[(size_t)m * N + n] = v;
        }
    }
}

// ---------------------------------------------------------------------------
// Kernel 5: FC3 [1024,1024] @ [20,1024]^T + bias -> d_out [1024,20]
// ---------------------------------------------------------------------------
__global__ __launch_bounds__(256) void k_fc3(
    const float* __restrict__ A, const float* __restrict__ W,
    const float* __restrict__ bias, float* __restrict__ out)
{
    __shared__ float row[1024];
    __shared__ float red[20][8];
    const int m = blockIdx.x;
    const int t = threadIdx.x;
    #pragma unroll
    for (int r = 0; r < 4; ++r) row[r * 256 + t] = A[(size_t)m * 1024 + r * 256 + t];
    __syncthreads();
    if (t < 160) {
        int o = t >> 3, seg = t & 7;
        const float* w = W + (size_t)o * 1024 + seg * 128;
        const float* rr = &row[seg * 128];
        float s = 0.f;
        for (int kk = 0; kk < 128; ++kk) s += rr[kk] * w[kk];
        red[o][seg] = s;
    }
    __syncthreads();
    if (t < 20) {
        float s = bias[t];
        #pragma unroll
        for (int seg = 0; seg < 8; ++seg) s += red[t][seg];
        out[(size_t)m * 20 + t] = s;
    }
}

// ---------------------------------------------------------------------------
extern "C" void kernel_launch(void* const* d_in, const int* in_sizes, int n_in,
                              void* d_out, int out_size, void* d_ws, size_t ws_size,
                              hipStream_t stream) {
    const float* in1    = (const float*)d_in[0];
    const float* in2    = (const float*)d_in[1];
    const float* w_x_q  = (const float*)d_in[2];
    const float* w_x_k  = (const float*)d_in[3];
    const float* w_y_q  = (const float*)d_in[4];
    const float* w_y_k  = (const float*)d_in[5];
    const float* posemb = (const float*)d_in[6];
    const float* conv_w = (const float*)d_in[7];
    const float* conv_b = (const float*)d_in[8];
    const float* bn_g   = (const float*)d_in[9];
    const float* bn_b   = (const float*)d_in[10];
    const float* bn_m   = (const float*)d_in[11];
    const float* bn_v   = (const float*)d_in[12];
    const float* Wih0   = (const float*)d_in[13];
    const float* Whh0   = (const float*)d_in[14];
    const float* bih0   = (const float*)d_in[15];
    const float* bhh0   = (const float*)d_in[16];
    const float* Wih1   = (const float*)d_in[17];
    const float* Whh1   = (const float*)d_in[18];
    const float* bih1   = (const float*)d_in[19];
    const float* bhh1   = (const float*)d_in[20];
    const float* fc1w   = (const float*)d_in[21];
    const float* fc1b   = (const float*)d_in[22];
    const float* fc2w   = (const float*)d_in[23];
    const float* fc2b   = (const float*)d_in[24];
    const float* fc3w   = (const float*)d_in[25];
    const float* fc3b   = (const float*)d_in[26];
    float* out = (float*)d_out;

    float* ws   = (float*)d_ws;
    float* pre0 = ws;                          // 8,421,888 floats (incl. prefetch pad)
    float* fbuf = ws + 8421888;                // 2,097,152
    float* f1   = ws + 10519040;               // 1,048,576
    float* f2   = ws + 11567616;               // 1,048,576
    unsigned short* Wh = (unsigned short*)(ws + 12616192);   // 30,720 ushorts
    unsigned short* Wl = Wh + 30720;                         // 30,720 ushorts

    k_permW<<<120, 256, 0, stream>>>(Wih0, Wh, Wl);
    k_attn_conv<<<1024, 256, 0, stream>>>(in1, in2, w_x_q, w_x_k, w_y_q, w_y_k,
                                          posemb, conv_w, conv_b, bn_g, bn_b,
                                          bn_m, bn_v, Wh, Wl, pre0);
    k_lstm<<<256, 64, 0, stream>>>(pre0, Whh0, Wih1, Whh1,
                                   bih0, bhh0, bih1, bhh1, fbuf);
    dim3 gfc(16, 16);
    k_fc<<<gfc, 256, 0, stream>>>(fbuf, fc1w, fc1b, f1, 1024, 1024, 2048, 1);
    k_fc<<<gfc, 256, 0, stream>>>(f1,   fc2w, fc2b, f2, 1024, 1024, 1024, 1);
    k_fc3<<<1024, 256, 0, stream>>>(f2, fc3w, fc3b, out);
}

// Round 4
// 454.224 us; speedup vs baseline: 2.0196x; 1.0052x over previous
//
#include <hip/hip_runtime.h>

// Problem constants: B=512, L=128, N=64, H=16, PW=30, FEAT=480
#define LSX 65    // xs row stride (64+1)
#define BST 40    // bf16 LDS row stride (32+8 ushorts, 16B-aligned)

typedef __bf16 bf16x8 __attribute__((ext_vector_type(8)));
typedef float  f32x4  __attribute__((ext_vector_type(4)));

__device__ __forceinline__ unsigned short f2bf_rne(float x) {
    unsigned int u = __float_as_uint(x);
    unsigned int r = u + 0x7FFFu + ((u >> 16) & 1u);
    return (unsigned short)(r >> 16);
}

// quad_perm broadcast of quad-lane Q (DPP ctrl = Q*0x55)
#define QB(x, C) __uint_as_float((unsigned)__builtin_amdgcn_update_dpp( \
        0, (int)__float_as_uint(x), (C), 0xF, 0xF, false))
#define RDLANE(x, L) __uint_as_float((unsigned)__builtin_amdgcn_readlane( \
        (int)__float_as_uint(x), (L)))

// ---------------------------------------------------------------------------
// Kernel 0: permute+split Wih0 [64,480] -> Wh/Wl [g][f'] bf16, f' = q*16+h
// ---------------------------------------------------------------------------
__global__ __launch_bounds__(256) void k_permW(const float* __restrict__ Wih0,
                                               unsigned short* __restrict__ Wh,
                                               unsigned short* __restrict__ Wl)
{
    int idx = blockIdx.x * 256 + threadIdx.x;     // < 30720 = 64*480
    int g = idx / 480, fp = idx % 480;
    int q = fp >> 4, h = fp & 15;
    float v = Wih0[g * 480 + h * 30 + q];
    unsigned int uv = __float_as_uint(v);
    unsigned short hb = (unsigned short)(uv >> 16);          // truncate
    float hf = __uint_as_float(uv & 0xFFFF0000u);
    Wh[idx] = hb;
    Wl[idx] = f2bf_rne(v - hf);
}

// ---------------------------------------------------------------------------
// Kernel 1: dual-axis attention + conv/bn/pool + MFMA GEMM (hi/lo bf16 split)
// grid = 1024 (i*512+b), block = 256 (4 waves)   [unchanged from round 3]
// ---------------------------------------------------------------------------
__global__ __launch_bounds__(256) void k_attn_conv(
    const float* __restrict__ x1, const float* __restrict__ x2,
    const float* __restrict__ w_x_q, const float* __restrict__ w_x_k,
    const float* __restrict__ w_y_q, const float* __restrict__ w_y_k,
    const float* __restrict__ pos_emb,
    const float* __restrict__ conv_w, const float* __restrict__ conv_b,
    const float* __restrict__ bn_g, const float* __restrict__ bn_b,
    const float* __restrict__ bn_m, const float* __restrict__ bn_v,
    const unsigned short* __restrict__ Whg, const unsigned short* __restrict__ Wlg,
    float* __restrict__ pre0)
{
    __shared__ float xs[128 * LSX];
    __shared__ unsigned short fh_s[128 * BST];
    __shared__ unsigned short fl_s[128 * BST];
    __shared__ unsigned short wh_s[64 * BST];
    __shared__ unsigned short wl_s[64 * BST];
    __shared__ float xk[64], ykv[128], uu[64], vv[128], sxs[128], sys[64];
    __shared__ float cw[16][4], cbs[16], bnsc[16], bnsh[16];

    const int bg = blockIdx.x;
    const int t  = threadIdx.x;
    const float* x = (bg < 512 ? x1 : x2) + (size_t)(bg & 511) * 8192;

    #pragma unroll
    for (int r = 0; r < 32; ++r) {
        int pos = r * 256 + t;
        xs[(pos >> 6) * LSX + (pos & 63)] = x[pos];
    }
    if (t < 16) {
        float sc = bn_g[t] * rsqrtf(bn_v[t] + 1e-5f);
        bnsc[t] = sc;
        bnsh[t] = bn_b[t] - bn_m[t] * sc;
        cbs[t]  = conv_b[t];
        cw[t][0] = conv_w[t * 4 + 0]; cw[t][1] = conv_w[t * 4 + 1];
        cw[t][2] = conv_w[t * 4 + 2]; cw[t][3] = conv_w[t * 4 + 3];
    }
    __syncthreads();

    if (t < 64) {
        float s = 0.f;
        for (int l = 0; l < 128; ++l) s += xs[l * LSX + t] * w_x_k[l];
        xk[t] = s;
    } else if (t < 192) {
        int l = t - 64;
        float s = 0.f;
        for (int n = 0; n < 64; ++n) s += w_y_k[n] * xs[l * LSX + n];
        ykv[l] = s;
    }
    __syncthreads();

    if (t < 64) {
        float s = 0.f;
        for (int n = 0; n < 64; ++n) s += w_x_q[t * 64 + n] * xk[n];
        uu[t] = s;
    } else if (t < 192) {
        int m = t - 64;
        float s = 0.f;
        for (int l = 0; l < 128; ++l) s += ykv[l] * w_y_q[l * 128 + m];
        vv[m] = s;
    }
    __syncthreads();

    if (t < 128) {
        float s = 0.f;
        for (int m = 0; m < 64; ++m) s += xs[t * LSX + m] * uu[m];
        sxs[t] = s;
    } else if (t < 192) {
        int n = t - 128;
        float s = 0.f;
        for (int m = 0; m < 128; ++m) s += vv[m] * xs[m * LSX + n];
        sys[n] = s;
    }
    __syncthreads();

    if (t < 64) {
        float a = sxs[t], b = sxs[t + 64];
        float mx = fmaxf(a, b);
        #pragma unroll
        for (int d = 32; d > 0; d >>= 1) mx = fmaxf(mx, __shfl_xor(mx, d, 64));
        float e0 = __expf(a - mx), e1 = __expf(b - mx);
        float s = e0 + e1;
        #pragma unroll
        for (int d = 32; d > 0; d >>= 1) s += __shfl_xor(s, d, 64);
        float r = 10.f / s;
        sxs[t] = e0 * r; sxs[t + 64] = e1 * r;
    } else if (t < 128) {
        int n = t - 64;
        float a = sys[n];
        float mx = a;
        #pragma unroll
        for (int d = 32; d > 0; d >>= 1) mx = fmaxf(mx, __shfl_xor(mx, d, 64));
        float e = __expf(a - mx);
        float s = e;
        #pragma unroll
        for (int d = 32; d > 0; d >>= 1) s += __shfl_xor(s, d, 64);
        sys[n] = e * (10.f / s);
    }
    __syncthreads();

    #pragma unroll
    for (int r = 0; r < 32; ++r) {
        int pos = r * 256 + t;
        int l = pos >> 6, n = pos & 63;
        xs[l * LSX + n] = xs[l * LSX + n] * sxs[l] * sys[n] + pos_emb[pos];
    }
    __syncthreads();

    const int lane = t & 63, w = t >> 6;
    const int m16 = lane & 15, kb = (lane >> 4) * 8;
    const int cl = t & 127, cqi = t >> 7;

    f32x4 acc[2][4];
    #pragma unroll
    for (int mt = 0; mt < 2; ++mt)
        #pragma unroll
        for (int nt = 0; nt < 4; ++nt) {
            f32x4 z = {0.f, 0.f, 0.f, 0.f};
            acc[mt][nt] = z;
        }

    for (int ch = 0; ch < 15; ++ch) {
        {
            int g = t >> 2, fb = (t & 3) * 8;
            size_t src = (size_t)g * 480 + ch * 32 + fb;
            *(uint4*)&wh_s[g * BST + fb] = *(const uint4*)(Whg + src);
            *(uint4*)&wl_s[g * BST + fb] = *(const uint4*)(Wlg + src);
        }
        {
            int q = ch * 2 + cqi;
            const float* xr = &xs[cl * LSX + 2 * q];
            float o0 = xr[0], o1 = xr[1], o2 = xr[2], o3 = xr[3], o4 = xr[4];
            union U8 { unsigned short s[8]; uint4 v; };
            U8 h0u, h1u, l0u, l1u;
            #pragma unroll
            for (int h = 0; h < 16; ++h) {
                float a = o0 * cw[h][0] + o1 * cw[h][1] + o2 * cw[h][2] + o3 * cw[h][3] + cbs[h];
                float b = o1 * cw[h][0] + o2 * cw[h][1] + o3 * cw[h][2] + o4 * cw[h][3] + cbs[h];
                a = fmaxf(a, 0.f) * bnsc[h] + bnsh[h];
                b = fmaxf(b, 0.f) * bnsc[h] + bnsh[h];
                float v = fmaxf(a, b);
                unsigned int uv = __float_as_uint(v);
                unsigned short hb = (unsigned short)(uv >> 16);
                float hf = __uint_as_float(uv & 0xFFFF0000u);
                unsigned short lb = f2bf_rne(v - hf);
                if (h < 8) { h0u.s[h] = hb; l0u.s[h] = lb; }
                else       { h1u.s[h - 8] = hb; l1u.s[h - 8] = lb; }
            }
            int base = cl * BST + cqi * 16;
            *(uint4*)&fh_s[base]     = h0u.v;
            *(uint4*)&fh_s[base + 8] = h1u.v;
            *(uint4*)&fl_s[base]     = l0u.v;
            *(uint4*)&fl_s[base + 8] = l1u.v;
        }
        __syncthreads();

        bf16x8 bh[4], bl[4], ah[2], al[2];
        #pragma unroll
        for (int nt = 0; nt < 4; ++nt) {
            int off = (nt * 16 + m16) * BST + kb;
            bh[nt] = *(const bf16x8*)&wh_s[off];
            bl[nt] = *(const bf16x8*)&wl_s[off];
        }
        #pragma unroll
        for (int mt = 0; mt < 2; ++mt) {
            int off = (w * 32 + mt * 16 + m16) * BST + kb;
            ah[mt] = *(const bf16x8*)&fh_s[off];
            al[mt] = *(const bf16x8*)&fl_s[off];
        }
        #pragma unroll
        for (int mt = 0; mt < 2; ++mt)
            #pragma unroll
            for (int nt = 0; nt < 4; ++nt) {
                acc[mt][nt] = __builtin_amdgcn_mfma_f32_16x16x32_bf16(ah[mt], bh[nt], acc[mt][nt], 0, 0, 0);
                acc[mt][nt] = __builtin_amdgcn_mfma_f32_16x16x32_bf16(al[mt], bh[nt], acc[mt][nt], 0, 0, 0);
                acc[mt][nt] = __builtin_amdgcn_mfma_f32_16x16x32_bf16(ah[mt], bl[nt], acc[mt][nt], 0, 0, 0);
            }
        __syncthreads();
    }

    #pragma unroll
    for (int mt = 0; mt < 2; ++mt)
        #pragma unroll
        for (int nt = 0; nt < 4; ++nt)
            #pragma unroll
            for (int r = 0; r < 4; ++r) {
                int row = w * 32 + mt * 16 + (lane >> 4) * 4 + r;
                int col = nt * 16 + m16;
                pre0[(size_t)bg * 8192 + row * 64 + col] = acc[mt][nt][r];
            }
}

// ---------------------------------------------------------------------------
// Kernel 2: fused 2-layer LSTM. 256 sequences, one wave each.
// Lane layout: lane = unit*4 + gate (gate 0=i,1=f,2=g,3=o; torch row = gate*16+unit).
// Own-gate activation only (sig/tanh unified), DPP quad broadcasts, readlane
// h-broadcast, 8-deep prefetch. No LDS, no barriers, no DS ops.
// ---------------------------------------------------------------------------
__global__ __launch_bounds__(64) void k_lstm(
    const float* __restrict__ pre0,
    const float* __restrict__ Whh0,
    const float* __restrict__ Wih1, const float* __restrict__ Whh1,
    const float* __restrict__ bih0, const float* __restrict__ bhh0,
    const float* __restrict__ bih1, const float* __restrict__ bhh1,
    float* __restrict__ fbuf)
{
    const int blk = blockIdx.x;
    const int i = blk >> 7, j = blk & 127;
    const int k = threadIdx.x;
    const int a = k & 3, u = k >> 2;
    const int row = a * 16 + u;          // torch gate-row index

    float w0[16], wi1[16], wh1[16];
    #pragma unroll
    for (int m = 0; m < 16; ++m) {
        w0[m]  = Whh0[row * 16 + m];
        wi1[m] = Wih1[row * 16 + m];
        wh1[m] = Whh1[row * 16 + m];
    }
    const float b0 = bih0[row] + bhh0[row];
    const float b1 = bih1[row] + bhh1[row];
    // unified activation: val = ka * (1/(1+exp(pm*g))) + kb
    //   sigmoid (gates i,f,o): pm=-1, ka=1, kb=0
    //   tanh    (gate g):      pm=-2, ka=2, kb=-1   (tanh(x)=2*sig(2x)-1)
    const float pm = (a == 2) ? -2.f : -1.f;
    const float ka = (a == 2) ?  2.f :  1.f;
    const float kb = (a == 2) ? -1.f :  0.f;

    float h0[16], h1[16];
    #pragma unroll
    for (int m = 0; m < 16; ++m) { h0[m] = 0.f; h1[m] = 0.f; }
    float c0 = 0.f, c1 = 0.f;

    const float* pp = pre0 + (size_t)i * 4194304 + (size_t)j * 64 + row;
    float* fbp = fbuf + (size_t)i * 1048576 + (size_t)j * 16 + u;
    const bool st = (a == 0);

    float pf[8];
    #pragma unroll
    for (int d = 0; d < 8; ++d) pf[d] = pp[(size_t)d * 8192];

#define LSTM_STEP(PRE, TT)                                                      \
    {                                                                           \
        float sA = 0.f, sB = 0.f, sC = 0.f, sD = 0.f;                           \
        _Pragma("unroll")                                                       \
        for (int m = 0; m < 4; ++m) {                                           \
            sA += h0[m]      * w0[m];                                           \
            sB += h0[m + 4]  * w0[m + 4];                                       \
            sC += h0[m + 8]  * w0[m + 8];                                       \
            sD += h0[m + 12] * w0[m + 12];                                      \
        }                                                                       \
        float g0 = PRE + b0 + ((sA + sB) + (sC + sD));                          \
        float e0 = __expf(pm * g0);                                             \
        float v0 = fmaf(__builtin_amdgcn_rcpf(1.f + e0), ka, kb);               \
        float si = QB(v0, 0x00), sf = QB(v0, 0x55);                             \
        float tg = QB(v0, 0xAA), so = QB(v0, 0xFF);                             \
        c0 = fmaf(sf, c0, si * tg);                                             \
        float ec = __expf(-2.f * c0);                                           \
        float h0n = so * fmaf(2.f, __builtin_amdgcn_rcpf(1.f + ec), -1.f);      \
        float hn[16];                                                           \
        _Pragma("unroll")                                                       \
        for (int m = 0; m < 16; ++m) hn[m] = RDLANE(h0n, 4 * m);                \
        float tA = 0.f, tB = 0.f, tC = 0.f, tD = 0.f;                           \
        _Pragma("unroll")                                                       \
        for (int m = 0; m < 4; ++m) {                                           \
            tA += hn[m]      * wi1[m]      + h1[m]      * wh1[m];               \
            tB += hn[m + 4]  * wi1[m + 4]  + h1[m + 4]  * wh1[m + 4];           \
            tC += hn[m + 8]  * wi1[m + 8]  + h1[m + 8]  * wh1[m + 8];           \
            tD += hn[m + 12] * wi1[m + 12] + h1[m + 12] * wh1[m + 12];          \
        }                                                                       \
        float g1 = b1 + ((tA + tB) + (tC + tD));                                \
        float e1 = __expf(pm * g1);                                             \
        float v1 = fmaf(__builtin_amdgcn_rcpf(1.f + e1), ka, kb);               \
        float si1 = QB(v1, 0x00), sf1 = QB(v1, 0x55);                           \
        float tg1 = QB(v1, 0xAA), so1 = QB(v1, 0xFF);                           \
        c1 = fmaf(sf1, c1, si1 * tg1);                                          \
        float ec1 = __expf(-2.f * c1);                                          \
        float h1n = so1 * fmaf(2.f, __builtin_amdgcn_rcpf(1.f + ec1), -1.f);    \
        if (st) fbp[(size_t)(TT) * 2048] = h1n;                                 \
        _Pragma("unroll")                                                       \
        for (int m = 0; m < 16; ++m) {                                          \
            h1[m] = RDLANE(h1n, 4 * m);                                         \
            h0[m] = hn[m];                                                      \
        }                                                                       \
    }

    for (int t = 0; t < 512; t += 8) {
        float nx[8];
        #pragma unroll
        for (int d = 0; d < 8; ++d) nx[d] = pp[(size_t)(t + 8 + d) * 8192];
        LSTM_STEP(pf[0], t + 0);
        LSTM_STEP(pf[1], t + 1);
        LSTM_STEP(pf[2], t + 2);
        LSTM_STEP(pf[3], t + 3);
        LSTM_STEP(pf[4], t + 4);
        LSTM_STEP(pf[5], t + 5);
        LSTM_STEP(pf[6], t + 6);
        LSTM_STEP(pf[7], t + 7);
        #pragma unroll
        for (int d = 0; d < 8; ++d) pf[d] = nx[d];
    }
#undef LSTM_STEP
}

// ---------------------------------------------------------------------------
// Kernel 3/4: MFMA bf16 hi/lo-split GEMM. C = leaky(A[M,K] @ W[N,K]^T + bias).
// block = 256 (2x2 waves), tile 128x128, BK=32. M,N,K multiples of 128/32.
// ---------------------------------------------------------------------------
#define FCS 40
__global__ __launch_bounds__(256) void k_fcmm(
    const float* __restrict__ A, const float* __restrict__ W,
    const float* __restrict__ bias, float* __restrict__ C,
    int M, int N, int K, int leaky)
{
    __shared__ unsigned short Ah[128 * FCS], Al[128 * FCS];
    __shared__ unsigned short Bh[128 * FCS], Bl[128 * FCS];
    const int t = threadIdx.x;
    const int lane = t & 63, w = t >> 6;
    const int wr = (w >> 1) * 64, wc = (w & 1) * 64;
    const int m0 = blockIdx.y * 128, n0 = blockIdx.x * 128;
    const int m16 = lane & 15, kb = (lane >> 4) * 8;
    const int sr = t >> 1, sc = (t & 1) * 16;

    f32x4 acc[4][4];
    #pragma unroll
    for (int mt = 0; mt < 4; ++mt)
        #pragma unroll
        for (int nt = 0; nt < 4; ++nt) {
            f32x4 z = {0.f, 0.f, 0.f, 0.f};
            acc[mt][nt] = z;
        }

    for (int kc = 0; kc < K; kc += 32) {
        const float* as = A + (size_t)(m0 + sr) * K + kc + sc;
        const float* bs = W + (size_t)(n0 + sr) * K + kc + sc;
        union U16 { unsigned short s[16]; uint4 v[2]; };
        U16 ha, la, hb, lb;
        #pragma unroll
        for (int q = 0; q < 16; q += 4) {
            float4 va = *(const float4*)(as + q);
            float4 vb = *(const float4*)(bs + q);
            float aa[4] = {va.x, va.y, va.z, va.w};
            float bb[4] = {vb.x, vb.y, vb.z, vb.w};
            #pragma unroll
            for (int e = 0; e < 4; ++e) {
                unsigned int ua = __float_as_uint(aa[e]);
                ha.s[q + e] = (unsigned short)(ua >> 16);
                la.s[q + e] = f2bf_rne(aa[e] - __uint_as_float(ua & 0xFFFF0000u));
                unsigned int ub = __float_as_uint(bb[e]);
                hb.s[q + e] = (unsigned short)(ub >> 16);
                lb.s[q + e] = f2bf_rne(bb[e] - __uint_as_float(ub & 0xFFFF0000u));
            }
        }
        int base = sr * FCS + sc;
        *(uint4*)&Ah[base] = ha.v[0]; *(uint4*)&Ah[base + 8] = ha.v[1];
        *(uint4*)&Al[base] = la.v[0]; *(uint4*)&Al[base + 8] = la.v[1];
        *(uint4*)&Bh[base] = hb.v[0]; *(uint4*)&Bh[base + 8] = hb.v[1];
        *(uint4*)&Bl[base] = lb.v[0]; *(uint4*)&Bl[base + 8] = lb.v[1];
        __syncthreads();

        bf16x8 afh[4], afl[4], bfh[4], bfl[4];
        #pragma unroll
        for (int mt = 0; mt < 4; ++mt) {
            int off = (wr + mt * 16 + m16) * FCS + kb;
            afh[mt] = *(const bf16x8*)&Ah[off];
            afl[mt] = *(const bf16x8*)&Al[off];
        }
        #pragma unroll
        for (int nt = 0; nt < 4; ++nt) {
            int off = (wc + nt * 16 + m16) * FCS + kb;
            bfh[nt] = *(const bf16x8*)&Bh[off];
            bfl[nt] = *(const bf16x8*)&Bl[off];
        }
        #pragma unroll
        for (int mt = 0; mt < 4; ++mt)
            #pragma unroll
            for (int nt = 0; nt < 4; ++nt) {
                acc[mt][nt] = __builtin_amdgcn_mfma_f32_16x16x32_bf16(afh[mt], bfh[nt], acc[mt][nt], 0, 0, 0);
                acc[mt][nt] = __builtin_amdgcn_mfma_f32_16x16x32_bf16(afl[mt], bfh[nt], acc[mt][nt], 0, 0, 0);
                acc[mt][nt] = __builtin_amdgcn_mfma_f32_16x16x32_bf16(afh[mt], bfl[nt], acc[mt][nt], 0, 0, 0);
            }
        __syncthreads();
    }

    #pragma unroll
    for (int mt = 0; mt < 4; ++mt)
        #pragma unroll
        for (int nt = 0; nt < 4; ++nt)
            #pragma unroll
            for (int r = 0; r < 4; ++r) {
                int row = m0 + wr + mt * 16 + (lane >> 4) * 4 + r;
                int col = n0 + wc + nt * 16 + m16;
                float v = acc[mt][nt][r] + bias[col];
                if (leaky) v = (v > 0.f) ? v : 0.01f * v;
                C[(size_t)row * N + col] = v;
            }
}

// ---------------------------------------------------------------------------
// Kernel 5: FC3 [1024,1024] @ [20,1024]^T + bias -> d_out [1024,20]
// ---------------------------------------------------------------------------
__global__ __launch_bounds__(256) void k_fc3(
    const float* __restrict__ A, const float* __restrict__ W,
    const float* __restrict__ bias, float* __restrict__ out)
{
    __shared__ float row[1024];
    __shared__ float red[20][8];
    const int m = blockIdx.x;
    const int t = threadIdx.x;
    #pragma unroll
    for (int r = 0; r < 4; ++r) row[r * 256 + t] = A[(size_t)m * 1024 + r * 256 + t];
    __syncthreads();
    if (t < 160) {
        int o = t >> 3, seg = t & 7;
        const float* w = W + (size_t)o * 1024 + seg * 128;
        const float* rr = &row[seg * 128];
        float s = 0.f;
        for (int kk = 0; kk < 128; ++kk) s += rr[kk] * w[kk];
        red[o][seg] = s;
    }
    __syncthreads();
    if (t < 20) {
        float s = bias[t];
        #pragma unroll
        for (int seg = 0; seg < 8; ++seg) s += red[t][seg];
        out[(size_t)m * 20 + t] = s;
    }
}

// ---------------------------------------------------------------------------
extern "C" void kernel_launch(void* const* d_in, const int* in_sizes, int n_in,
                              void* d_out, int out_size, void* d_ws, size_t ws_size,
                              hipStream_t stream) {
    const float* in1    = (const float*)d_in[0];
    const float* in2    = (const float*)d_in[1];
    const float* w_x_q  = (const float*)d_in[2];
    const float* w_x_k  = (const float*)d_in[3];
    const float* w_y_q  = (const float*)d_in[4];
    const float* w_y_k  = (const float*)d_in[5];
    const float* posemb = (const float*)d_in[6];
    const float* conv_w = (const float*)d_in[7];
    const float* conv_b = (const float*)d_in[8];
    const float* bn_g   = (const float*)d_in[9];
    const float* bn_b   = (const float*)d_in[10];
    const float* bn_m   = (const float*)d_in[11];
    const float* bn_v   = (const float*)d_in[12];
    const float* Wih0   = (const float*)d_in[13];
    const float* Whh0   = (const float*)d_in[14];
    const float* bih0   = (const float*)d_in[15];
    const float* bhh0   = (const float*)d_in[16];
    const float* Wih1   = (const float*)d_in[17];
    const float* Whh1   = (const float*)d_in[18];
    const float* bih1   = (const float*)d_in[19];
    const float* bhh1   = (const float*)d_in[20];
    const float* fc1w   = (const float*)d_in[21];
    const float* fc1b   = (const float*)d_in[22];
    const float* fc2w   = (const float*)d_in[23];
    const float* fc2b   = (const float*)d_in[24];
    const float* fc3w   = (const float*)d_in[25];
    const float* fc3b   = (const float*)d_in[26];
    float* out = (float*)d_out;

    float* ws   = (float*)d_ws;
    float* pre0 = ws;                          // 8,454,144 floats (8-step prefetch pad)
    float* fbuf = ws + 8454144;                // 2,097,152
    float* f1   = ws + 10551296;               // 1,048,576
    float* f2   = ws + 11599872;               // 1,048,576
    unsigned short* Wh = (unsigned short*)(ws + 12648448);   // 30,720 ushorts
    unsigned short* Wl = Wh + 30720;                         // 30,720 ushorts

    k_permW<<<120, 256, 0, stream>>>(Wih0, Wh, Wl);
    k_attn_conv<<<1024, 256, 0, stream>>>(in1, in2, w_x_q, w_x_k, w_y_q, w_y_k,
                                          posemb, conv_w, conv_b, bn_g, bn_b,
                                          bn_m, bn_v, Wh, Wl, pre0);
    k_lstm<<<256, 64, 0, stream>>>(pre0, Whh0, Wih1, Whh1,
                                   bih0, bhh0, bih1, bhh1, fbuf);
    dim3 gfc(8, 8);
    k_fcmm<<<gfc, 256, 0, stream>>>(fbuf, fc1w, fc1b, f1, 1024, 1024, 2048, 1);
    k_fcmm<<<gfc, 256, 0, stream>>>(f1,   fc2w, fc2b, f2, 1024, 1024, 1024, 1);
    k_fc3<<<1024, 256, 0, stream>>>(f2, fc3w, fc3b, out);
}

// Round 5
// 390.003 us; speedup vs baseline: 2.3522x; 1.1647x over previous
//
#include <hip/hip_runtime.h>

// Problem constants: B=512, L=128, N=64, H=16, PW=30, FEAT=480
#define LSX 65    // xs row stride (64+1)
#define FCS 40    // fcmm LDS row stride (32+8 ushorts)

typedef __bf16 bf16x8 __attribute__((ext_vector_type(8)));
typedef float  f32x4  __attribute__((ext_vector_type(4)));

__device__ __forceinline__ unsigned short f2bf_rne(float x) {
    unsigned int u = __float_as_uint(x);
    unsigned int r = u + 0x7FFFu + ((u >> 16) & 1u);
    return (unsigned short)(r >> 16);
}

// quad_perm broadcast of quad-lane Q (DPP ctrl = Q*0x55)
#define QB(x, C) __uint_as_float((unsigned)__builtin_amdgcn_update_dpp( \
        0, (int)__float_as_uint(x), (C), 0xF, 0xF, false))
#define RDLANE(x, L) __uint_as_float((unsigned)__builtin_amdgcn_readlane( \
        (int)__float_as_uint(x), (L)))

// ---------------------------------------------------------------------------
// Kernel 0: Wih0 [64,480] -> MFMA B-fragment layout, bf16 hi/lo:
// Wf[((ch*4+nt)*64 + lane)*8 + j] = Wih0[g*480 + h*30 + q]
//   g = nt*16 + (lane&15); k = (lane>>4)*8 + j; f = ch*32+k; q = f>>4; h = f&15
// ---------------------------------------------------------------------------
__global__ __launch_bounds__(256) void k_permW(const float* __restrict__ Wih0,
                                               unsigned short* __restrict__ Wfh,
                                               unsigned short* __restrict__ Wfl)
{
    int idx = blockIdx.x * 256 + threadIdx.x;     // < 30720
    int j = idx & 7, lane = (idx >> 3) & 63, nt = (idx >> 9) & 3, ch = idx >> 11;
    int g = nt * 16 + (lane & 15);
    int k = (lane >> 4) * 8 + j;
    int f = ch * 32 + k, q = f >> 4, h = f & 15;
    float v = Wih0[g * 480 + h * 30 + q];
    unsigned int uv = __float_as_uint(v);
    Wfh[idx] = (unsigned short)(uv >> 16);
    Wfl[idx] = f2bf_rne(v - __uint_as_float(uv & 0xFFFF0000u));
}

// ---------------------------------------------------------------------------
// Kernel 0b: generic fp32 -> bf16 hi/lo split (per float4)
// ---------------------------------------------------------------------------
__global__ __launch_bounds__(256) void k_cvt(const float* __restrict__ in,
                                             unsigned short* __restrict__ oh,
                                             unsigned short* __restrict__ ol,
                                             int n4)
{
    int i = blockIdx.x * 256 + threadIdx.x;
    if (i >= n4) return;
    float4 v = ((const float4*)in)[i];
    float vv[4] = {v.x, v.y, v.z, v.w};
    unsigned short hs[4], ls[4];
    #pragma unroll
    for (int e = 0; e < 4; ++e) {
        unsigned int u = __float_as_uint(vv[e]);
        hs[e] = (unsigned short)(u >> 16);
        ls[e] = f2bf_rne(vv[e] - __uint_as_float(u & 0xFFFF0000u));
    }
    uint2 ph = make_uint2((unsigned)hs[0] | ((unsigned)hs[1] << 16),
                          (unsigned)hs[2] | ((unsigned)hs[3] << 16));
    uint2 pl = make_uint2((unsigned)ls[0] | ((unsigned)ls[1] << 16),
                          (unsigned)ls[2] | ((unsigned)ls[3] << 16));
    *(uint2*)&oh[i * 4] = ph;
    *(uint2*)&ol[i * 4] = pl;
}

// ---------------------------------------------------------------------------
// Kernel 1: dual-axis attention + conv/bn/pool + MFMA GEMM.
// Phase 6 v3: conv params in registers, feat computed directly as MFMA
// A-fragments in registers, W fragments loaded from global (L2-resident).
// No LDS staging, no barriers in the K-loop. grid = 1024, block = 256.
// ---------------------------------------------------------------------------
__global__ __launch_bounds__(256, 3) void k_attn_conv(
    const float* __restrict__ x1, const float* __restrict__ x2,
    const float* __restrict__ w_x_q, const float* __restrict__ w_x_k,
    const float* __restrict__ w_y_q, const float* __restrict__ w_y_k,
    const float* __restrict__ pos_emb,
    const float* __restrict__ conv_w, const float* __restrict__ conv_b,
    const float* __restrict__ bn_g, const float* __restrict__ bn_b,
    const float* __restrict__ bn_m, const float* __restrict__ bn_v,
    const unsigned short* __restrict__ Wfh, const unsigned short* __restrict__ Wfl,
    float* __restrict__ pre0)
{
    __shared__ float xs[128 * LSX];
    __shared__ float xk[64], ykv[128], uu[64], vv[128], sxs[128], sys[64];
    __shared__ float cw[16][4], cbs[16], bnsc[16], bnsh[16];

    const int bg = blockIdx.x;
    const int t  = threadIdx.x;
    const float* x = (bg < 512 ? x1 : x2) + (size_t)(bg & 511) * 8192;

    #pragma unroll
    for (int r = 0; r < 32; ++r) {
        int pos = r * 256 + t;
        xs[(pos >> 6) * LSX + (pos & 63)] = x[pos];
    }
    if (t < 16) {
        float sc = bn_g[t] * rsqrtf(bn_v[t] + 1e-5f);
        bnsc[t] = sc;
        bnsh[t] = bn_b[t] - bn_m[t] * sc;
        cbs[t]  = conv_b[t];
        cw[t][0] = conv_w[t * 4 + 0]; cw[t][1] = conv_w[t * 4 + 1];
        cw[t][2] = conv_w[t * 4 + 2]; cw[t][3] = conv_w[t * 4 + 3];
    }
    __syncthreads();

    // phase 1: x_k[n], y_kv[l]
    if (t < 64) {
        float s = 0.f;
        for (int l = 0; l < 128; ++l) s += xs[l * LSX + t] * w_x_k[l];
        xk[t] = s;
    } else if (t < 192) {
        int l = t - 64;
        float s = 0.f;
        for (int n = 0; n < 64; ++n) s += w_y_k[n] * xs[l * LSX + n];
        ykv[l] = s;
    }
    __syncthreads();

    // phase 2: u[m], v[m]
    if (t < 64) {
        float s = 0.f;
        for (int n = 0; n < 64; ++n) s += w_x_q[t * 64 + n] * xk[n];
        uu[t] = s;
    } else if (t < 192) {
        int m = t - 64;
        float s = 0.f;
        for (int l = 0; l < 128; ++l) s += ykv[l] * w_y_q[l * 128 + m];
        vv[m] = s;
    }
    __syncthreads();

    // phase 3: s_x[l], y_[n]
    if (t < 128) {
        float s = 0.f;
        for (int m = 0; m < 64; ++m) s += xs[t * LSX + m] * uu[m];
        sxs[t] = s;
    } else if (t < 192) {
        int n = t - 128;
        float s = 0.f;
        for (int m = 0; m < 128; ++m) s += vv[m] * xs[m * LSX + n];
        sys[n] = s;
    }
    __syncthreads();

    // phase 4: softmaxes, x10
    if (t < 64) {
        float a = sxs[t], b = sxs[t + 64];
        float mx = fmaxf(a, b);
        #pragma unroll
        for (int d = 32; d > 0; d >>= 1) mx = fmaxf(mx, __shfl_xor(mx, d, 64));
        float e0 = __expf(a - mx), e1 = __expf(b - mx);
        float s = e0 + e1;
        #pragma unroll
        for (int d = 32; d > 0; d >>= 1) s += __shfl_xor(s, d, 64);
        float r = 10.f / s;
        sxs[t] = e0 * r; sxs[t + 64] = e1 * r;
    } else if (t < 128) {
        int n = t - 64;
        float a = sys[n];
        float mx = a;
        #pragma unroll
        for (int d = 32; d > 0; d >>= 1) mx = fmaxf(mx, __shfl_xor(mx, d, 64));
        float e = __expf(a - mx);
        float s = e;
        #pragma unroll
        for (int d = 32; d > 0; d >>= 1) s += __shfl_xor(s, d, 64);
        sys[n] = e * (10.f / s);
    }
    __syncthreads();

    // phase 5: out = x*sx*sy + pos_emb (in place)
    #pragma unroll
    for (int r = 0; r < 32; ++r) {
        int pos = r * 256 + t;
        int l = pos >> 6, n = pos & 63;
        xs[l * LSX + n] = xs[l * LSX + n] * sxs[l] * sys[n] + pos_emb[pos];
    }
    __syncthreads();

    // phase 6: 15 chunks of K=32; in-register feat + global W frags
    const int lane = t & 63, w = t >> 6;
    const int m16 = lane & 15, kq = lane >> 4;
    const int hb = (kq & 1) * 8;          // this lane's 8 channels
    const int qoff = kq >> 1;             // q within chunk

    float cwr0[8], cwr1[8], cwr2[8], cwr3[8], cbr[8], bsr[8], bhr[8];
    #pragma unroll
    for (int j = 0; j < 8; ++j) {
        cwr0[j] = cw[hb + j][0]; cwr1[j] = cw[hb + j][1];
        cwr2[j] = cw[hb + j][2]; cwr3[j] = cw[hb + j][3];
        cbr[j] = cbs[hb + j]; bsr[j] = bnsc[hb + j]; bhr[j] = bnsh[hb + j];
    }

    f32x4 acc[2][4];
    #pragma unroll
    for (int mt = 0; mt < 2; ++mt)
        #pragma unroll
        for (int nt = 0; nt < 4; ++nt) {
            f32x4 z = {0.f, 0.f, 0.f, 0.f};
            acc[mt][nt] = z;
        }

    for (int ch = 0; ch < 15; ++ch) {
        bf16x8 bh[4], bl[4];
        #pragma unroll
        for (int nt = 0; nt < 4; ++nt) {
            int o = ((ch * 4 + nt) * 64 + lane) * 8;
            bh[nt] = *(const bf16x8*)&Wfh[o];
            bl[nt] = *(const bf16x8*)&Wfl[o];
        }
        bf16x8 ah[2], al[2];
        const int q2 = 2 * (2 * ch + qoff);
        #pragma unroll
        for (int mt = 0; mt < 2; ++mt) {
            int row = w * 32 + mt * 16 + m16;
            const float* xr = &xs[row * LSX + q2];
            float o0 = xr[0], o1 = xr[1], o2 = xr[2], o3 = xr[3], o4 = xr[4];
            union { unsigned short us[8]; bf16x8 bv; } vh, vl;
            #pragma unroll
            for (int j = 0; j < 8; ++j) {
                float a = fmaf(o0, cwr0[j], fmaf(o1, cwr1[j], fmaf(o2, cwr2[j], fmaf(o3, cwr3[j], cbr[j]))));
                float b = fmaf(o1, cwr0[j], fmaf(o2, cwr1[j], fmaf(o3, cwr2[j], fmaf(o4, cwr3[j], cbr[j]))));
                a = fmaf(fmaxf(a, 0.f), bsr[j], bhr[j]);
                b = fmaf(fmaxf(b, 0.f), bsr[j], bhr[j]);
                float v = fmaxf(a, b);
                unsigned int uv = __float_as_uint(v);
                vh.us[j] = (unsigned short)(uv >> 16);
                vl.us[j] = f2bf_rne(v - __uint_as_float(uv & 0xFFFF0000u));
            }
            ah[mt] = vh.bv; al[mt] = vl.bv;
        }
        #pragma unroll
        for (int mt = 0; mt < 2; ++mt)
            #pragma unroll
            for (int nt = 0; nt < 4; ++nt) {
                acc[mt][nt] = __builtin_amdgcn_mfma_f32_16x16x32_bf16(ah[mt], bh[nt], acc[mt][nt], 0, 0, 0);
                acc[mt][nt] = __builtin_amdgcn_mfma_f32_16x16x32_bf16(al[mt], bh[nt], acc[mt][nt], 0, 0, 0);
                acc[mt][nt] = __builtin_amdgcn_mfma_f32_16x16x32_bf16(ah[mt], bl[nt], acc[mt][nt], 0, 0, 0);
            }
    }

    // C/D layout: col = lane&15, row = (lane>>4)*4 + reg
    #pragma unroll
    for (int mt = 0; mt < 2; ++mt)
        #pragma unroll
        for (int nt = 0; nt < 4; ++nt)
            #pragma unroll
            for (int r = 0; r < 4; ++r) {
                int row = w * 32 + mt * 16 + (lane >> 4) * 4 + r;
                int col = nt * 16 + m16;
                pre0[(size_t)bg * 8192 + row * 64 + col] = acc[mt][nt][r];
            }
}

// ---------------------------------------------------------------------------
// Kernel 2: fused 2-layer LSTM, software-pipelined: each iteration computes
// {L1(t) || L0(t+1)} — two independent chains sharing h0s(t). One wave per
// sequence; lane = unit*4 + gate; DPP quad broadcasts; grouped readlanes.
// Emits fbuf directly as bf16 hi/lo for the fc1 MFMA GEMM.
// ---------------------------------------------------------------------------
__global__ __launch_bounds__(64) void k_lstm(
    const float* __restrict__ pre0,
    const float* __restrict__ Whh0,
    const float* __restrict__ Wih1, const float* __restrict__ Whh1,
    const float* __restrict__ bih0, const float* __restrict__ bhh0,
    const float* __restrict__ bih1, const float* __restrict__ bhh1,
    unsigned short* __restrict__ fbh, unsigned short* __restrict__ fbl)
{
    const int blk = blockIdx.x;
    const int i = blk >> 7, j = blk & 127;
    const int k = threadIdx.x;
    const int a = k & 3, u = k >> 2;
    const int row = a * 16 + u;

    float w0[16], wi1[16], wh1[16];
    #pragma unroll
    for (int m = 0; m < 16; ++m) {
        w0[m]  = Whh0[row * 16 + m];
        wi1[m] = Wih1[row * 16 + m];
        wh1[m] = Whh1[row * 16 + m];
    }
    const float b0 = bih0[row] + bhh0[row];
    const float b1 = bih1[row] + bhh1[row];
    const float pm = (a == 2) ? -2.f : -1.f;
    const float ka = (a == 2) ?  2.f :  1.f;
    const float kb = (a == 2) ? -1.f :  0.f;

    float h0s[16], h1s[16];
    #pragma unroll
    for (int m = 0; m < 16; ++m) { h0s[m] = 0.f; h1s[m] = 0.f; }
    float c0 = 0.f, c1 = 0.f;

    const float* pp = pre0 + (size_t)i * 4194304 + (size_t)j * 64 + row;
    const size_t fbase = (size_t)i * 1048576 + (size_t)j * 16 + u;
    const bool st = (a == 0);

    // prologue: L0(0)  (h0 state is zero)
    {
        float g0 = pp[0] + b0;
        float e0 = __expf(pm * g0);
        float v0 = fmaf(__builtin_amdgcn_rcpf(1.f + e0), ka, kb);
        float si = QB(v0, 0x00), tg = QB(v0, 0xAA), so = QB(v0, 0xFF);
        c0 = si * tg;
        float ec = __expf(-2.f * c0);
        float h0n = so * fmaf(2.f, __builtin_amdgcn_rcpf(1.f + ec), -1.f);
        #pragma unroll
        for (int m = 0; m < 16; ++m) h0s[m] = RDLANE(h0n, 4 * m);
    }

    float pf[8];
    #pragma unroll
    for (int d = 0; d < 8; ++d) pf[d] = pp[(size_t)(1 + d) * 8192];

#define STEP2(PF, TT)                                                           \
    {                                                                           \
        float tA = 0.f, tB = 0.f, tC = 0.f, tD = 0.f;                           \
        float sA = 0.f, sB = 0.f, sC = 0.f, sD = 0.f;                           \
        _Pragma("unroll")                                                       \
        for (int m = 0; m < 4; ++m) {                                           \
            tA += h0s[m]      * wi1[m]      + h1s[m]      * wh1[m];             \
            tB += h0s[m + 4]  * wi1[m + 4]  + h1s[m + 4]  * wh1[m + 4];         \
            tC += h0s[m + 8]  * wi1[m + 8]  + h1s[m + 8]  * wh1[m + 8];         \
            tD += h0s[m + 12] * wi1[m + 12] + h1s[m + 12] * wh1[m + 12];        \
            sA += h0s[m]      * w0[m];                                          \
            sB += h0s[m + 4]  * w0[m + 4];                                      \
            sC += h0s[m + 8]  * w0[m + 8];                                      \
            sD += h0s[m + 12] * w0[m + 12];                                     \
        }                                                                       \
        float g1 = b1 + ((tA + tB) + (tC + tD));                                \
        float g0 = (PF) + b0 + ((sA + sB) + (sC + sD));                         \
        float e1 = __expf(pm * g1);                                             \
        float e0 = __expf(pm * g0);                                             \
        float v1 = fmaf(__builtin_amdgcn_rcpf(1.f + e1), ka, kb);               \
        float v0 = fmaf(__builtin_amdgcn_rcpf(1.f + e0), ka, kb);               \
        float si1 = QB(v1, 0x00), sf1 = QB(v1, 0x55);                           \
        float tg1 = QB(v1, 0xAA), so1 = QB(v1, 0xFF);                           \
        float si0 = QB(v0, 0x00), sf0 = QB(v0, 0x55);                           \
        float tg0 = QB(v0, 0xAA), so0 = QB(v0, 0xFF);                           \
        c1 = fmaf(sf1, c1, si1 * tg1);                                          \
        c0 = fmaf(sf0, c0, si0 * tg0);                                          \
        float ec1 = __expf(-2.f * c1);                                          \
        float ec0 = __expf(-2.f * c0);                                          \
        float h1n = so1 * fmaf(2.f, __builtin_amdgcn_rcpf(1.f + ec1), -1.f);    \
        float h0n = so0 * fmaf(2.f, __builtin_amdgcn_rcpf(1.f + ec0), -1.f);    \
        if (st) {                                                               \
            unsigned int uh = __float_as_uint(h1n);                             \
            fbh[fbase + (size_t)(TT) * 2048] = (unsigned short)(uh >> 16);      \
            fbl[fbase + (size_t)(TT) * 2048] =                                  \
                f2bf_rne(h1n - __uint_as_float(uh & 0xFFFF0000u));              \
        }                                                                       \
        _Pragma("unroll")                                                       \
        for (int m = 0; m < 16; ++m) h1s[m] = RDLANE(h1n, 4 * m);               \
        _Pragma("unroll")                                                       \
        for (int m = 0; m < 16; ++m) h0s[m] = RDLANE(h0n, 4 * m);               \
    }

    for (int tb = 0; tb < 64; ++tb) {
        const int base = tb * 8;
        float nx[8];
        #pragma unroll
        for (int d = 0; d < 8; ++d) nx[d] = pp[(size_t)(base + 9 + d) * 8192];
        STEP2(pf[0], base + 0);
        STEP2(pf[1], base + 1);
        STEP2(pf[2], base + 2);
        STEP2(pf[3], base + 3);
        STEP2(pf[4], base + 4);
        STEP2(pf[5], base + 5);
        STEP2(pf[6], base + 6);
        STEP2(pf[7], base + 7);
        #pragma unroll
        for (int d = 0; d < 8; ++d) pf[d] = nx[d];
    }
#undef STEP2
}

// ---------------------------------------------------------------------------
// Kernel 3/4: MFMA bf16 GEMM on pre-split hi/lo inputs.
// C = leaky(A[M,K] @ W[N,K]^T + bias); output either f32 (Cf) or split (Ch/Cl).
// block = 256 (2x2 waves), tile 128x128, BK=32.
// ---------------------------------------------------------------------------
__global__ __launch_bounds__(256) void k_fcmm(
    const unsigned short* __restrict__ Ahg, const unsigned short* __restrict__ Alg,
    const unsigned short* __restrict__ Bhg, const unsigned short* __restrict__ Blg,
    const float* __restrict__ bias,
    float* __restrict__ Cf, unsigned short* __restrict__ Chh,
    unsigned short* __restrict__ Chl,
    int N, int K)
{
    __shared__ unsigned short Ah[128 * FCS], Al[128 * FCS];
    __shared__ unsigned short Bh[128 * FCS], Bl[128 * FCS];
    const int t = threadIdx.x;
    const int lane = t & 63, w = t >> 6;
    const int wr = (w >> 1) * 64, wc = (w & 1) * 64;
    const int m0 = blockIdx.y * 128, n0 = blockIdx.x * 128;
    const int m16 = lane & 15, kb = (lane >> 4) * 8;

    f32x4 acc[4][4];
    #pragma unroll
    for (int mt = 0; mt < 4; ++mt)
        #pragma unroll
        for (int nt = 0; nt < 4; ++nt) {
            f32x4 z = {0.f, 0.f, 0.f, 0.f};
            acc[mt][nt] = z;
        }

    for (int kc = 0; kc < K; kc += 32) {
        #pragma unroll
        for (int si = 0; si < 2; ++si) {
            int s = t * 2 + si;
            int r = s >> 2, kg = (s & 3) * 8;
            size_t ga = (size_t)(m0 + r) * K + kc + kg;
            size_t gb = (size_t)(n0 + r) * K + kc + kg;
            *(uint4*)&Ah[r * FCS + kg] = *(const uint4*)&Ahg[ga];
            *(uint4*)&Al[r * FCS + kg] = *(const uint4*)&Alg[ga];
            *(uint4*)&Bh[r * FCS + kg] = *(const uint4*)&Bhg[gb];
            *(uint4*)&Bl[r * FCS + kg] = *(const uint4*)&Blg[gb];
        }
        __syncthreads();

        bf16x8 afh[4], afl[4], bfh[4], bfl[4];
        #pragma unroll
        for (int mt = 0; mt < 4; ++mt) {
            int off = (wr + mt * 16 + m16) * FCS + kb;
            afh[mt] = *(const bf16x8*)&Ah[off];
            afl[mt] = *(const bf16x8*)&Al[off];
        }
        #pragma unroll
        for (int nt = 0; nt < 4; ++nt) {
            int off = (wc + nt * 16 + m16) * FCS + kb;
            bfh[nt] = *(const bf16x8*)&Bh[off];
            bfl[nt] = *(const bf16x8*)&Bl[off];
        }
        #pragma unroll
        for (int mt = 0; mt < 4; ++mt)
            #pragma unroll
            for (int nt = 0; nt < 4; ++nt) {
                acc[mt][nt] = __builtin_amdgcn_mfma_f32_16x16x32_bf16(afh[mt], bfh[nt], acc[mt][nt], 0, 0, 0);
                acc[mt][nt] = __builtin_amdgcn_mfma_f32_16x16x32_bf16(afl[mt], bfh[nt], acc[mt][nt], 0, 0, 0);
                acc[mt][nt] = __builtin_amdgcn_mfma_f32_16x16x32_bf16(afh[mt], bfl[nt], acc[mt][nt], 0, 0, 0);
            }
        __syncthreads();
    }

    #pragma unroll
    for (int mt = 0; mt < 4; ++mt)
        #pragma unroll
        for (int nt = 0; nt < 4; ++nt)
            #pragma unroll
            for (int r = 0; r < 4; ++r) {
                int rr = m0 + wr + mt * 16 + (lane >> 4) * 4 + r;
                int cc = n0 + wc + nt * 16 + m16;
                float v = acc[mt][nt][r] + bias[cc];
                v = (v > 0.f) ? v : 0.01f * v;
                if (Cf) {
                    Cf[(size_t)rr * N + cc] = v;
                } else {
                    unsigned int uv = __float_as_uint(v);
                    Chh[(size_t)rr * N + cc] = (unsigned short)(uv >> 16);
                    Chl[(size_t)rr * N + cc] =
                        f2bf_rne(v - __uint_as_float(uv & 0xFFFF0000u));
                }
            }
}

// ---------------------------------------------------------------------------
// Kernel 5: FC3 [1024,1024] @ [20,1024]^T + bias -> d_out [1024,20]
// ---------------------------------------------------------------------------
__global__ __launch_bounds__(256) void k_fc3(
    const float* __restrict__ A, const float* __restrict__ W,
    const float* __restrict__ bias, float* __restrict__ out)
{
    __shared__ float row[1024];
    __shared__ float red[20][8];
    const int m = blockIdx.x;
    const int t = threadIdx.x;
    #pragma unroll
    for (int r = 0; r < 4; ++r) row[r * 256 + t] = A[(size_t)m * 1024 + r * 256 + t];
    __syncthreads();
    if (t < 160) {
        int o = t >> 3, seg = t & 7;
        const float* w = W + (size_t)o * 1024 + seg * 128;
        const float* rr = &row[seg * 128];
        float s = 0.f;
        for (int kk = 0; kk < 128; ++kk) s += rr[kk] * w[kk];
        red[o][seg] = s;
    }
    __syncthreads();
    if (t < 20) {
        float s = bias[t];
        #pragma unroll
        for (int seg = 0; seg < 8; ++seg) s += red[t][seg];
        out[(size_t)m * 20 + t] = s;
    }
}

// ---------------------------------------------------------------------------
extern "C" void kernel_launch(void* const* d_in, const int* in_sizes, int n_in,
                              void* d_out, int out_size, void* d_ws, size_t ws_size,
                              hipStream_t stream) {
    const float* in1    = (const float*)d_in[0];
    const float* in2    = (const float*)d_in[1];
    const float* w_x_q  = (const float*)d_in[2];
    const float* w_x_k  = (const float*)d_in[3];
    const float* w_y_q  = (const float*)d_in[4];
    const float* w_y_k  = (const float*)d_in[5];
    const float* posemb = (const float*)d_in[6];
    const float* conv_w = (const float*)d_in[7];
    const float* conv_b = (const float*)d_in[8];
    const float* bn_g   = (const float*)d_in[9];
    const float* bn_b   = (const float*)d_in[10];
    const float* bn_m   = (const float*)d_in[11];
    const float* bn_v   = (const float*)d_in[12];
    const float* Wih0   = (const float*)d_in[13];
    const float* Whh0   = (const float*)d_in[14];
    const float* bih0   = (const float*)d_in[15];
    const float* bhh0   = (const float*)d_in[16];
    const float* Wih1   = (const float*)d_in[17];
    const float* Whh1   = (const float*)d_in[18];
    const float* bih1   = (const float*)d_in[19];
    const float* bhh1   = (const float*)d_in[20];
    const float* fc1w   = (const float*)d_in[21];
    const float* fc1b   = (const float*)d_in[22];
    const float* fc2w   = (const float*)d_in[23];
    const float* fc2b   = (const float*)d_in[24];
    const float* fc3w   = (const float*)d_in[25];
    const float* fc3b   = (const float*)d_in[26];
    float* out = (float*)d_out;

    float* ws = (float*)d_ws;
    // float-slot offsets
    float* pre0            = ws;                               // 8,466,432
    unsigned short* fbh    = (unsigned short*)(ws + 8466432);  // 2,097,152 us
    unsigned short* fbl    = (unsigned short*)(ws + 9515008);
    unsigned short* f1h    = (unsigned short*)(ws + 10563584); // 1,048,576 us
    unsigned short* f1l    = (unsigned short*)(ws + 11087872);
    float* f2              = ws + 11612160;                    // 1,048,576 f
    unsigned short* w1h    = (unsigned short*)(ws + 12660736); // 2,097,152 us
    unsigned short* w1l    = (unsigned short*)(ws + 13709312);
    unsigned short* w2h    = (unsigned short*)(ws + 14757888); // 1,048,576 us
    unsigned short* w2l    = (unsigned short*)(ws + 15282176);
    unsigned short* Wfh    = (unsigned short*)(ws + 15806464); // 30,720 us
    unsigned short* Wfl    = (unsigned short*)(ws + 15821824);

    k_permW<<<120, 256, 0, stream>>>(Wih0, Wfh, Wfl);
    k_cvt<<<2048, 256, 0, stream>>>(fc1w, w1h, w1l, 524288);
    k_cvt<<<1024, 256, 0, stream>>>(fc2w, w2h, w2l, 262144);
    k_attn_conv<<<1024, 256, 0, stream>>>(in1, in2, w_x_q, w_x_k, w_y_q, w_y_k,
                                          posemb, conv_w, conv_b, bn_g, bn_b,
                                          bn_m, bn_v, Wfh, Wfl, pre0);
    k_lstm<<<256, 64, 0, stream>>>(pre0, Whh0, Wih1, Whh1,
                                   bih0, bhh0, bih1, bhh1, fbh, fbl);
    dim3 gfc(8, 8);
    k_fcmm<<<gfc, 256, 0, stream>>>(fbh, fbl, w1h, w1l, fc1b,
                                    nullptr, f1h, f1l, 1024, 2048);
    k_fcmm<<<gfc, 256, 0, stream>>>(f1h, f1l, w2h, w2l, fc2b,
                                    f2, nullptr, nullptr, 1024, 1024);
    k_fc3<<<1024, 256, 0, stream>>>(f2, fc3w, fc3b, out);
}